// Round 5
// baseline (279.765 us; speedup 1.0000x reference)
//
#include <hip/hip_runtime.h>
#include <float.h>
#include <math.h>

#define NUM_USERS 100000
#define NUM_ITEMS 50000
#define NNODES    150000
#define DIM       64
#define NEDGE     2000000
#define BATCH     1024
#define SEL_CAP   (1 << 18)
#define LOGIT_BLOCKS 512

#define SLICES   1024                   // edge slices (4 blocks/CU on 256 CUs)
#define EPS      1956                   // ceil(NEDGE/SLICES) rounded to x4
#define NBUK     293                    // buckets of 512 nodes (293*512=150016)

__device__ __forceinline__ float wave_sum64(float v) {
    #pragma unroll
    for (int off = 32; off > 0; off >>= 1) v += __shfl_xor(v, off, 64);
    return v;
}

__device__ __forceinline__ float bf2f(unsigned short s) {
    return __uint_as_float(((unsigned int)s) << 16);
}
__device__ __forceinline__ unsigned short f2bf(float f) {   // RNE
    unsigned int u = __float_as_uint(f);
    return (unsigned short)((u + 0x7fffu + ((u >> 16) & 1u)) >> 16);
}

// ---- stage 1: per-slice 293-bucket histograms + u8 ranks + fused selection

__global__ __launch_bounds__(512) void bhist_kernel(
        const int* __restrict__ row, const int* __restrict__ col,
        const int* __restrict__ ucnt,
        unsigned short* __restrict__ cntR, unsigned short* __restrict__ cntC,
        unsigned char* __restrict__ rkR, unsigned char* __restrict__ rkC,
        int* __restrict__ n_sel, int* __restrict__ sel_col, float* __restrict__ sel_w) {
    __shared__ unsigned int hr[NBUK], hc[NBUK];
    __shared__ int lcnt, lbase;
    __shared__ int2 buf[256];
    int blk = blockIdx.x, t = threadIdx.x;
    for (int i = t; i < NBUK; i += 512) { hr[i] = 0; hc[i] = 0; }
    if (t == 0) lcnt = 0;
    __syncthreads();
    int e0 = blk * EPS;
    int e1 = e0 + EPS; if (e1 > NEDGE) e1 = NEDGE;
    for (int base = e0 + t * 4; base < e1; base += 2048) {
        if (base + 4 <= e1) {
            int4 r4 = *(const int4*)(row + base);
            int4 c4 = *(const int4*)(col + base);
            uchar4 a, b;
            a.x = (unsigned char)atomicAdd(&hr[r4.x >> 9], 1u);
            a.y = (unsigned char)atomicAdd(&hr[r4.y >> 9], 1u);
            a.z = (unsigned char)atomicAdd(&hr[r4.z >> 9], 1u);
            a.w = (unsigned char)atomicAdd(&hr[r4.w >> 9], 1u);
            b.x = (unsigned char)atomicAdd(&hc[c4.x >> 9], 1u);
            b.y = (unsigned char)atomicAdd(&hc[c4.y >> 9], 1u);
            b.z = (unsigned char)atomicAdd(&hc[c4.z >> 9], 1u);
            b.w = (unsigned char)atomicAdd(&hc[c4.w >> 9], 1u);
            *(uchar4*)(rkR + base) = a;
            *(uchar4*)(rkC + base) = b;
            int u0 = ucnt[r4.x], u1 = ucnt[r4.y], u2 = ucnt[r4.z], u3 = ucnt[r4.w];
            if (u0 > 0) { int i = atomicAdd(&lcnt, 1); if (i < 256) buf[i] = make_int2(c4.x, u0); }
            if (u1 > 0) { int i = atomicAdd(&lcnt, 1); if (i < 256) buf[i] = make_int2(c4.y, u1); }
            if (u2 > 0) { int i = atomicAdd(&lcnt, 1); if (i < 256) buf[i] = make_int2(c4.z, u2); }
            if (u3 > 0) { int i = atomicAdd(&lcnt, 1); if (i < 256) buf[i] = make_int2(c4.w, u3); }
        } else {
            for (int e = base; e < e1; ++e) {
                int r = row[e], c = col[e];
                rkR[e] = (unsigned char)atomicAdd(&hr[r >> 9], 1u);
                rkC[e] = (unsigned char)atomicAdd(&hc[c >> 9], 1u);
                int u = ucnt[r];
                if (u > 0) { int i = atomicAdd(&lcnt, 1); if (i < 256) buf[i] = make_int2(c, u); }
            }
        }
    }
    __syncthreads();
    for (int i = t; i < NBUK; i += 512) {
        cntR[(size_t)blk * NBUK + i] = (unsigned short)hr[i];
        cntC[(size_t)blk * NBUK + i] = (unsigned short)hc[i];
    }
    if (t == 0) {
        int c = lcnt; c = c < 256 ? c : 256;
        lbase = atomicAdd(n_sel, c);
    }
    __syncthreads();
    int c = lcnt; c = c < 256 ? c : 256;
    int b = lbase;
    for (int i = t; i < c; i += 512) {
        int o = b + i;
        if (o < SEL_CAP) { sel_col[o] = buf[i].x; sel_w[o] = (float)buf[i].y; }
    }
}

// ---- stage 2: per-bucket prefix over 1024 slices (2 slices/thread) -------

__global__ __launch_bounds__(512) void bprefix1_kernel(
        const unsigned short* __restrict__ cntR, const unsigned short* __restrict__ cntC,
        unsigned short* __restrict__ offR, unsigned short* __restrict__ offC,
        int* __restrict__ totRC) {
    int side = blockIdx.x / NBUK;
    int b = blockIdx.x - side * NBUK;
    const unsigned short* cnt = side ? cntC : cntR;
    unsigned short* off = side ? offC : offR;
    __shared__ int sm[512];
    int t = threadIdx.x;
    int v0 = (int)cnt[(size_t)(2 * t) * NBUK + b];
    int v1 = (int)cnt[(size_t)(2 * t + 1) * NBUK + b];
    int p = v0 + v1;
    sm[t] = p;
    __syncthreads();
    for (int o = 1; o < 512; o <<= 1) {
        int x = (t >= o) ? sm[t - o] : 0;
        __syncthreads();
        sm[t] += x;
        __syncthreads();
    }
    int excl = sm[t] - p;
    off[(size_t)(2 * t) * NBUK + b]     = (unsigned short)excl;
    off[(size_t)(2 * t + 1) * NBUK + b] = (unsigned short)(excl + v0);
    if (t == 511) totRC[side * NBUK + b] = sm[511];
}

__global__ __launch_bounds__(512) void bprefix2_kernel(
        const int* __restrict__ totRC, int* __restrict__ baseR, int* __restrict__ baseC) {
    const int* tot = totRC + blockIdx.x * NBUK;
    int* base = blockIdx.x ? baseC : baseR;
    __shared__ int sm[512];
    int t = threadIdx.x;
    int v = (t < NBUK) ? tot[t] : 0;
    sm[t] = v;
    __syncthreads();
    for (int o = 1; o < 512; o <<= 1) {
        int x = (t >= o) ? sm[t - o] : 0;
        __syncthreads();
        sm[t] += x;
        __syncthreads();
    }
    if (t < NBUK) base[t] = sm[t] - v;
    if (t == NBUK - 1) base[NBUK] = sm[t];     // == NEDGE
}

// ---- stage 3: placement -- LDS slice sort, flat full-lane write-out ------

__global__ __launch_bounds__(512) void place_kernel(
        const int* __restrict__ row, const int* __restrict__ col,
        const unsigned char* __restrict__ rkR, const unsigned char* __restrict__ rkC,
        const unsigned short* __restrict__ cntR, const unsigned short* __restrict__ cntC,
        const unsigned short* __restrict__ offR, const unsigned short* __restrict__ offC,
        const int* __restrict__ baseR, const int* __restrict__ baseC,
        unsigned short* __restrict__ midR, unsigned int* __restrict__ midC) {
    __shared__ int lofC[NBUK], lofR[NBUK], posC[NBUK], posR[NBUK];
    __shared__ int cCl[NBUK], cRl[NBUK];
    __shared__ int scan_tmp[512];
    __shared__ unsigned int   stC[EPS];
    __shared__ unsigned short stR[EPS];
    __shared__ unsigned short bmapC[EPS], bmapR[EPS];
    int blk = blockIdx.x, t = threadIdx.x;
    if (t < NBUK) {
        cCl[t] = (int)cntC[(size_t)blk * NBUK + t];
        cRl[t] = (int)cntR[(size_t)blk * NBUK + t];
        posC[t] = baseC[t] + (int)offC[(size_t)blk * NBUK + t];
        posR[t] = baseR[t] + (int)offR[(size_t)blk * NBUK + t];
    }
    __syncthreads();
    scan_tmp[t] = (t < NBUK) ? cCl[t] : 0;
    __syncthreads();
    for (int o = 1; o < 512; o <<= 1) {
        int v = (t >= o) ? scan_tmp[t - o] : 0;
        __syncthreads();
        scan_tmp[t] += v;
        __syncthreads();
    }
    if (t < NBUK) lofC[t] = scan_tmp[t] - cCl[t];
    __syncthreads();
    scan_tmp[t] = (t < NBUK) ? cRl[t] : 0;
    __syncthreads();
    for (int o = 1; o < 512; o <<= 1) {
        int v = (t >= o) ? scan_tmp[t - o] : 0;
        __syncthreads();
        scan_tmp[t] += v;
        __syncthreads();
    }
    if (t < NBUK) lofR[t] = scan_tmp[t] - cRl[t];
    __syncthreads();
    // j -> bucket maps (stC/stR are bucket-contiguous after scatter)
    if (t < NBUK) {
        int c = cCl[t], lo = lofC[t];
        for (int k = 0; k < c; ++k) bmapC[lo + k] = (unsigned short)t;
        c = cRl[t]; lo = lofR[t];
        for (int k = 0; k < c; ++k) bmapR[lo + k] = (unsigned short)t;
    }
    int e0 = blk * EPS;
    int e1 = e0 + EPS; if (e1 > NEDGE) e1 = NEDGE;
    for (int base = e0 + t * 4; base < e1; base += 2048) {
        if (base + 4 <= e1) {
            int4 r4 = *(const int4*)(row + base);
            int4 c4 = *(const int4*)(col + base);
            uchar4 kr = *(const uchar4*)(rkR + base);
            uchar4 kc = *(const uchar4*)(rkC + base);
            stC[lofC[c4.x >> 9] + (int)kc.x] = ((unsigned int)(c4.x & 511) << 18) | (unsigned int)r4.x;
            stC[lofC[c4.y >> 9] + (int)kc.y] = ((unsigned int)(c4.y & 511) << 18) | (unsigned int)r4.y;
            stC[lofC[c4.z >> 9] + (int)kc.z] = ((unsigned int)(c4.z & 511) << 18) | (unsigned int)r4.z;
            stC[lofC[c4.w >> 9] + (int)kc.w] = ((unsigned int)(c4.w & 511) << 18) | (unsigned int)r4.w;
            stR[lofR[r4.x >> 9] + (int)kr.x] = (unsigned short)(r4.x & 511);
            stR[lofR[r4.y >> 9] + (int)kr.y] = (unsigned short)(r4.y & 511);
            stR[lofR[r4.z >> 9] + (int)kr.z] = (unsigned short)(r4.z & 511);
            stR[lofR[r4.w >> 9] + (int)kr.w] = (unsigned short)(r4.w & 511);
        } else {
            for (int e = base; e < e1; ++e) {
                int r = row[e], c = col[e];
                stC[lofC[c >> 9] + (int)rkC[e]] = ((unsigned int)(c & 511) << 18) | (unsigned int)r;
                stR[lofR[r >> 9] + (int)rkR[e]] = (unsigned short)(r & 511);
            }
        }
    }
    __syncthreads();
    // flat write-out: consecutive j -> mostly-consecutive global dst
    int total = e1 - e0;
    for (int j = t; j < total; j += 512) {
        int b = bmapC[j];
        midC[posC[b] + (j - lofC[b])] = stC[j];
        b = bmapR[j];
        midR[posR[b] + (j - lofR[b])] = stR[j];
    }
}

// ---- stage 4 (fused): col CSR + row deg/dinv + embed->bf16 y0 ------------

__global__ __launch_bounds__(1024) void bfinal_kernel(
        const unsigned int* __restrict__ midC, const int* __restrict__ baseC,
        const unsigned short* __restrict__ midR, const int* __restrict__ baseR,
        const float4* __restrict__ embed,
        int* __restrict__ rptr, int* __restrict__ src_sorted,
        float* __restrict__ dinv, float* __restrict__ dinv2,
        uint2* __restrict__ y0) {
    __shared__ int cnt[512], sm[512], cur[512];
    __shared__ float dinvL[512];
    int b = blockIdx.x, t = threadIdx.x;
    // --- col part ---
    int s0 = baseC[b], s1 = baseC[b + 1];
    if (t < 512) cnt[t] = 0;
    __syncthreads();
    for (int i = s0 + t; i < s1; i += 1024) atomicAdd(&cnt[midC[i] >> 18], 1);
    __syncthreads();
    if (t < 512) sm[t] = cnt[t];
    __syncthreads();
    for (int off = 1; off < 512; off <<= 1) {
        int v = 0;
        if (t < 512 && t >= off) v = sm[t - off];
        __syncthreads();
        if (t < 512) sm[t] += v;
        __syncthreads();
    }
    if (t < 512) {
        int excl = s0 + sm[t] - cnt[t];
        int n = b * 512 + t;
        if (n < NNODES) rptr[n] = excl;
        cur[t] = excl;
    }
    if (b == NBUK - 1 && t == 0) rptr[NNODES] = s1;   // == NEDGE
    if (b == 0 && t < 16) y0[(size_t)NNODES * 16 + t] = make_uint2(0u, 0u); // sentinel zero row
    __syncthreads();
    for (int i = s0 + t; i < s1; i += 1024) {
        unsigned int v = midC[i];
        int dst = atomicAdd(&cur[v >> 18], 1);
        src_sorted[dst] = (int)(v & 0x3FFFFu);
    }
    __syncthreads();
    // --- row part ---
    if (t < 512) cnt[t] = 0;
    __syncthreads();
    int r0 = baseR[b], r1 = baseR[b + 1];
    for (int i = r0 + t; i < r1; i += 1024) atomicAdd(&cnt[midR[i]], 1);
    __syncthreads();
    if (t < 512) {
        int n = b * 512 + t;
        if (n < NNODES) {
            float d = fmaxf((float)cnt[t], 1.0f);
            float di = rsqrtf(d);
            dinv[n] = di; dinv2[n] = 1.0f / d;
            dinvL[t] = di;
        }
    }
    __syncthreads();
    // --- cvt part: y0 = bf16(dinv * embed) for this node range ---
    int nbase = b * 512;
    int nmax = NNODES - nbase; if (nmax > 512) nmax = 512;
    if (nmax < 0) nmax = 0;
    for (int i = t; i < nmax * 16; i += 1024) {
        int ln = i >> 4, slot = i & 15;
        float d = dinvL[ln];
        float4 v = embed[(size_t)(nbase + ln) * 16 + slot];
        unsigned int w0 = (unsigned int)f2bf(v.x * d) | ((unsigned int)f2bf(v.y * d) << 16);
        unsigned int w1 = (unsigned int)f2bf(v.z * d) | ((unsigned int)f2bf(v.w * d) << 16);
        y0[(size_t)(nbase + ln) * 16 + slot] = make_uint2(w0, w1);
    }
}

// ---- propagation: 8 lanes/node, uint4 (8 bf16)/lane; src-prefetch pipeline,
//      parallel sentinel tail (node NNODES is an always-zero row) -----------

#define ACC8(V) do { \
    a0 += __uint_as_float((V).x << 16); a1 += __uint_as_float((V).x & 0xffff0000u); \
    a2 += __uint_as_float((V).y << 16); a3 += __uint_as_float((V).y & 0xffff0000u); \
    a4 += __uint_as_float((V).z << 16); a5 += __uint_as_float((V).z & 0xffff0000u); \
    a6 += __uint_as_float((V).w << 16); a7 += __uint_as_float((V).w & 0xffff0000u); \
} while (0)

// shared gather body: accumulate neighbors of `node`, write x_out row
__device__ __forceinline__ void prop_node(
        const uint4* __restrict__ x_in, uint4* __restrict__ x_out,
        const int* __restrict__ ptr, const int* __restrict__ src,
        const float* __restrict__ scale, int node, int sl) {
    int i = ptr[node], e = ptr[node + 1];
    float sc = scale[node];
    float a0 = 0.f, a1 = 0.f, a2 = 0.f, a3 = 0.f;
    float a4 = 0.f, a5 = 0.f, a6 = 0.f, a7 = 0.f;
    int p0, p1, p2, p3;
    if (i + 4 <= e) { p0 = src[i]; p1 = src[i + 1]; p2 = src[i + 2]; p3 = src[i + 3]; }
    while (i + 8 <= e) {
        uint4 w0 = x_in[p0 * 8 + sl];
        uint4 w1 = x_in[p1 * 8 + sl];
        uint4 w2 = x_in[p2 * 8 + sl];
        uint4 w3 = x_in[p3 * 8 + sl];
        p0 = src[i + 4]; p1 = src[i + 5]; p2 = src[i + 6]; p3 = src[i + 7];
        i += 4;
        ACC8(w0); ACC8(w1); ACC8(w2); ACC8(w3);
    }
    if (i + 4 <= e) {
        uint4 w0 = x_in[p0 * 8 + sl];
        uint4 w1 = x_in[p1 * 8 + sl];
        uint4 w2 = x_in[p2 * 8 + sl];
        uint4 w3 = x_in[p3 * 8 + sl];
        i += 4;
        ACC8(w0); ACC8(w1); ACC8(w2); ACC8(w3);
    }
    if (i < e) {               // tail 1..3: clamp to sentinel zero row
        int q0 = src[i];
        int q1 = (i + 1 < e) ? src[i + 1] : NNODES;
        int q2 = (i + 2 < e) ? src[i + 2] : NNODES;
        uint4 w0 = x_in[q0 * 8 + sl];
        uint4 w1 = x_in[q1 * 8 + sl];
        uint4 w2 = x_in[q2 * 8 + sl];
        ACC8(w0); ACC8(w1); ACC8(w2);
    }
    uint4 o;
    o.x = (unsigned int)f2bf(a0 * sc) | ((unsigned int)f2bf(a1 * sc) << 16);
    o.y = (unsigned int)f2bf(a2 * sc) | ((unsigned int)f2bf(a3 * sc) << 16);
    o.z = (unsigned int)f2bf(a4 * sc) | ((unsigned int)f2bf(a5 * sc) << 16);
    o.w = (unsigned int)f2bf(a6 * sc) | ((unsigned int)f2bf(a7 * sc) << 16);
    x_out[(size_t)node * 8 + sl] = o;
}

__global__ __launch_bounds__(256, 8) void prop_kernel(
        const uint4* __restrict__ x_in, uint4* __restrict__ x_out,
        const int* __restrict__ ptr, const int* __restrict__ src,
        const float* __restrict__ scale) {
    int gid  = blockIdx.x * blockDim.x + threadIdx.x;
    int node = gid >> 3;       // 8 lanes per node
    int sl   = gid & 7;        // lane's 8-dim slot within the row
    if (node > NNODES) return;
    if (node == NNODES) {      // keep sentinel row zero for next layer
        x_out[(size_t)node * 8 + sl] = make_uint4(0u, 0u, 0u, 0u);
        return;
    }
    prop_node(x_in, x_out, ptr, src, scale, node, sl);
}

// layer 3: only nodes consumed downstream — users, items+NUM_USERS, sel_col.
// Duplicates recompute bit-identical rows (same CSR order) -> benign.
__global__ __launch_bounds__(256, 8) void prop_list_kernel(
        const uint4* __restrict__ x_in, uint4* __restrict__ x_out,
        const int* __restrict__ ptr, const int* __restrict__ src,
        const float* __restrict__ scale,
        const int* __restrict__ users, const int* __restrict__ items,
        const int* __restrict__ sel_col, const int* __restrict__ n_sel_p) {
    int gid = blockIdx.x * blockDim.x + threadIdx.x;
    int li  = gid >> 3;        // list index
    int sl  = gid & 7;
    int node;
    if (li < BATCH) {
        node = users[li];
    } else if (li < 2 * BATCH) {
        node = items[li - BATCH] + NUM_USERS;
    } else {
        int j = li - 2 * BATCH;
        int n = *n_sel_p; if (n > SEL_CAP) n = SEL_CAP;
        if (j >= n) return;
        node = sel_col[j];
    }
    prop_node(x_in, x_out, ptr, src, scale, node, sl);
}

// ---- batch / softmax part (x is bf16) -----------------------------------

__global__ void ucnt_kernel(const int* __restrict__ users, int* __restrict__ ucnt) {
    int b = blockIdx.x * blockDim.x + threadIdx.x;
    if (b < BATCH) atomicAdd(&ucnt[users[b]], 1);
}

__global__ __launch_bounds__(256) void ctx_part_kernel(
        const unsigned short* __restrict__ x, const int* __restrict__ users,
        float* __restrict__ partial) {
    __shared__ float sm[256];
    int lane = threadIdx.x & 63, wl = threadIdx.x >> 6;
    int b = blockIdx.x * 4 + wl;
    float v = (b < BATCH) ? bf2f(x[users[b] * DIM + lane]) : 0.0f;
    sm[threadIdx.x] = v;
    __syncthreads();
    if (wl == 0)
        partial[blockIdx.x * 64 + lane] =
            sm[lane] + sm[64 + lane] + sm[128 + lane] + sm[192 + lane];
}

__global__ __launch_bounds__(256) void ctx_reduce_kernel(
        const float* __restrict__ partial, float* __restrict__ ctx) {
    __shared__ float sm[256];
    int lane = threadIdx.x & 63, wl = threadIdx.x >> 6;
    float acc = 0.0f;
    for (int i = wl; i < 256; i += 4) acc += partial[i * 64 + lane];
    sm[threadIdx.x] = acc;
    __syncthreads();
    if (wl == 0)
        ctx[lane] = (sm[lane] + sm[64 + lane] + sm[128 + lane] + sm[192 + lane])
                    * (1.0f / BATCH);
}

__global__ void softmax_kernel(const unsigned short* __restrict__ x,
                               const float* __restrict__ ctx,
                               const int* __restrict__ sel_col,
                               const float* __restrict__ sel_w,
                               const int* __restrict__ n_sel_p,
                               float* __restrict__ S, float* __restrict__ zp) {
    __shared__ float smS[4 * 64];
    __shared__ float smZ[4];
    int lane = threadIdx.x & 63, wl = threadIdx.x >> 6;
    int n = *n_sel_p; if (n > SEL_CAP) n = SEL_CAP;
    float c = ctx[lane];
    float accS = 0.0f, accZ = 0.0f;
    int stride = gridDim.x * 4;
    for (int idx = blockIdx.x * 4 + wl; idx < n; idx += stride) {
        int node = sel_col[idx];
        float xv = bf2f(x[node * DIM + lane]);
        float v = wave_sum64(xv * c);
        float w = sel_w[idx] * __expf(v);
        accS = fmaf(w, xv, accS);
        accZ += w;
    }
    smS[wl * 64 + lane] = accS;
    if (lane == 0) smZ[wl] = accZ;
    __syncthreads();
    if (wl == 0) {
        float s = smS[lane] + smS[64 + lane] + smS[128 + lane] + smS[192 + lane];
        atomicAdd(&S[lane], s);
    }
    if (threadIdx.x == 0) atomicAdd(zp, smZ[0] + smZ[1] + smZ[2] + smZ[3]);
}

__global__ void score_kernel(const unsigned short* __restrict__ x, const int* __restrict__ users,
                             const int* __restrict__ items, const float* __restrict__ S,
                             const float* __restrict__ zp, float* __restrict__ out) {
    int gid = blockIdx.x * blockDim.x + threadIdx.x;
    int b = gid >> 6, lane = gid & 63;
    if (b >= BATCH) return;
    float z = fmaxf(*zp, 1e-12f);
    float na = S[lane] / z;
    int u = users[b], it = items[b] + NUM_USERS;
    float v = bf2f(x[u * DIM + lane]) * (bf2f(x[it * DIM + lane]) + na);
    v = wave_sum64(v);
    if (lane == 0) out[b] = 1.0f / (1.0f + __expf(-v));
}

// ---- launch -------------------------------------------------------------

extern "C" void kernel_launch(void* const* d_in, const int* in_sizes, int n_in,
                              void* d_out, int out_size, void* d_ws, size_t ws_size,
                              hipStream_t stream) {
    const float* embed = (const float*)d_in[0];
    const int*   edge  = (const int*)d_in[1];
    const int*   row   = edge;
    const int*   col   = edge + NEDGE;
    const int*   users = (const int*)d_in[2];
    const int*   items = (const int*)d_in[3];
    float*       out   = (float*)d_out;
    char*        ws    = (char*)d_ws;

    size_t off = 0;
    auto A = [&](size_t bytes) { size_t o = off; off += (bytes + 255) & ~(size_t)255; return o; };
    size_t o_mid   = A((size_t)NEDGE * 4 + (size_t)NEDGE * 2);  // midC 8MB + midR 4MB
    size_t o_xa    = A((size_t)(NNODES + 1) * DIM * 2);     // +1: sentinel zero row
    size_t o_xb    = A((size_t)(NNODES + 1) * DIM * 2);
    size_t o_src   = A((size_t)NEDGE * 4);             // 8 MB, alive thru prop
    size_t o_rkR   = A((size_t)SLICES * EPS);          // 2 MB
    size_t o_rkC   = A((size_t)SLICES * EPS);          // 2 MB
    size_t o_cntR  = A((size_t)SLICES * NBUK * 2);     // 600 KB
    size_t o_cntC  = A((size_t)SLICES * NBUK * 2);
    size_t o_offR  = A((size_t)SLICES * NBUK * 2);
    size_t o_offC  = A((size_t)SLICES * NBUK * 2);
    size_t o_tot   = A((size_t)2 * NBUK * 4);
    size_t o_baseR = A((size_t)(NBUK + 1) * 4);
    size_t o_baseC = A((size_t)(NBUK + 1) * 4);
    size_t o_selc  = A((size_t)SEL_CAP * 4);
    size_t o_selw  = A((size_t)SEL_CAP * 4);
    size_t o_part  = A((size_t)256 * 64 * 4);          // ctx partials
    size_t o_zero  = off;                              // ---- zeroed block ----
    size_t o_ucnt  = A((size_t)NNODES * 4);
    size_t o_misc  = A(1024);                          // n_sel@0, z@8, S@256
    size_t zero_bytes = off - o_zero;                  // ---- end zero -------
    size_t o_dinv  = A((size_t)NNODES * 4);
    size_t o_dinv2 = A((size_t)NNODES * 4);
    size_t o_rptr  = A((size_t)(NNODES + 1) * 4);
    size_t o_ctx   = A(256);

    unsigned int*   midC = (unsigned int*)(ws + o_mid);
    unsigned short* midR = (unsigned short*)(ws + o_mid + (size_t)NEDGE * 4);
    unsigned short* xa   = (unsigned short*)(ws + o_xa);
    unsigned short* xb   = (unsigned short*)(ws + o_xb);
    int*   srcS  = (int*)(ws + o_src);
    unsigned char* rkR = (unsigned char*)(ws + o_rkR);
    unsigned char* rkC = (unsigned char*)(ws + o_rkC);
    unsigned short* cntR = (unsigned short*)(ws + o_cntR);
    unsigned short* cntC = (unsigned short*)(ws + o_cntC);
    unsigned short* offR = (unsigned short*)(ws + o_offR);
    unsigned short* offC = (unsigned short*)(ws + o_offC);
    int*   totRC = (int*)(ws + o_tot);
    int*   baseR = (int*)(ws + o_baseR);
    int*   baseC = (int*)(ws + o_baseC);
    int*   selc  = (int*)(ws + o_selc);
    float* selw  = (float*)(ws + o_selw);
    float* part  = (float*)(ws + o_part);
    int*   ucnt  = (int*)(ws + o_ucnt);
    int*   nsel  = (int*)(ws + o_misc);
    float* zp    = (float*)(ws + o_misc + 8);
    float* S     = (float*)(ws + o_misc + 256);
    float* dinv  = (float*)(ws + o_dinv);
    float* dinv2 = (float*)(ws + o_dinv2);
    int*   rptr  = (int*)(ws + o_rptr);
    float* ctx   = (float*)(ws + o_ctx);

    hipMemsetAsync(ws + o_zero, 0, zero_bytes, stream);

    ucnt_kernel<<<(BATCH + 255) / 256, 256, 0, stream>>>(users, ucnt);

    // atomic-free CSR build (selection fused into bhist)
    bhist_kernel<<<SLICES, 512, 0, stream>>>(row, col, ucnt, cntR, cntC, rkR, rkC,
                                             nsel, selc, selw);
    bprefix1_kernel<<<2 * NBUK, 512, 0, stream>>>(cntR, cntC, offR, offC, totRC);
    bprefix2_kernel<<<2, 512, 0, stream>>>(totRC, baseR, baseC);
    place_kernel<<<SLICES, 512, 0, stream>>>(row, col, rkR, rkC, cntR, cntC,
                                             offR, offC, baseR, baseC, midR, midC);
    // fused: col CSR + row deg + embed->y0 conversion
    bfinal_kernel<<<NBUK, 1024, 0, stream>>>(midC, baseC, midR, baseR,
                                             (const float4*)embed, rptr, srcS,
                                             dinv, dinv2, (uint2*)xa);

    // layers 1,2 full: y->y (dinv2), y->y (dinv2); layer 3 selective: y->x (dinv)
    int prop_blocks = ((NNODES + 1) * 8 + 255) / 256;
    prop_kernel<<<prop_blocks, 256, 0, stream>>>((const uint4*)xa, (uint4*)xb, rptr, srcS, dinv2);
    prop_kernel<<<prop_blocks, 256, 0, stream>>>((const uint4*)xb, (uint4*)xa, rptr, srcS, dinv2);
    int list_blocks = ((2 * BATCH + SEL_CAP) * 8 + 255) / 256;
    prop_list_kernel<<<list_blocks, 256, 0, stream>>>((const uint4*)xa, (uint4*)xb,
                                                      rptr, srcS, dinv,
                                                      users, items, selc, nsel);
    // final x rows (users/items/sel) live in xb

    // batch softmax aggregation over selected edges (mx = 0, fused)
    ctx_part_kernel<<<256, 256, 0, stream>>>(xb, users, part);
    ctx_reduce_kernel<<<1, 256, 0, stream>>>(part, ctx);
    softmax_kernel<<<LOGIT_BLOCKS, 256, 0, stream>>>(xb, ctx, selc, selw, nsel, S, zp);

    // final scores
    score_kernel<<<(BATCH * 64 + 255) / 256, 256, 0, stream>>>(xb, users, items, S, zp, out);
}

// Round 6
// 262.688 us; speedup vs baseline: 1.0650x; 1.0650x over previous
//
#include <hip/hip_runtime.h>
#include <float.h>
#include <math.h>

#define NUM_USERS 100000
#define NUM_ITEMS 50000
#define NNODES    150000
#define DIM       64
#define NEDGE     2000000
#define BATCH     1024
#define SEL_CAP   (1 << 18)
#define LOGIT_BLOCKS 512

#define SLICES   1024                   // edge slices
#define EPS      1956                   // ceil(NEDGE/SLICES) rounded to x4
#define NBUK     293                    // buckets of 512 nodes (293*512=150016)

__device__ __forceinline__ float wave_sum64(float v) {
    #pragma unroll
    for (int off = 32; off > 0; off >>= 1) v += __shfl_xor(v, off, 64);
    return v;
}

__device__ __forceinline__ float bf2f(unsigned short s) {
    return __uint_as_float(((unsigned int)s) << 16);
}
__device__ __forceinline__ unsigned short f2bf(float f) {   // RNE
    unsigned int u = __float_as_uint(f);
    return (unsigned short)((u + 0x7fffu + ((u >> 16) & 1u)) >> 16);
}

// ---- stage 1: per-slice 293-bucket histograms (count only) + selection ---

__global__ __launch_bounds__(512) void bhist_kernel(
        const int* __restrict__ row, const int* __restrict__ col,
        const int* __restrict__ ucnt,
        unsigned short* __restrict__ cntR, unsigned short* __restrict__ cntC,
        int* __restrict__ n_sel, int* __restrict__ sel_col, float* __restrict__ sel_w) {
    __shared__ unsigned int hr[NBUK], hc[NBUK];
    __shared__ int lcnt, lbase;
    __shared__ int2 buf[256];
    int blk = blockIdx.x, t = threadIdx.x;
    for (int i = t; i < NBUK; i += 512) { hr[i] = 0; hc[i] = 0; }
    if (t == 0) lcnt = 0;
    __syncthreads();
    int e0 = blk * EPS;
    int e1 = e0 + EPS; if (e1 > NEDGE) e1 = NEDGE;
    for (int base = e0 + t * 4; base < e1; base += 2048) {
        if (base + 4 <= e1) {
            int4 r4 = *(const int4*)(row + base);
            int4 c4 = *(const int4*)(col + base);
            atomicAdd(&hr[r4.x >> 9], 1u);
            atomicAdd(&hr[r4.y >> 9], 1u);
            atomicAdd(&hr[r4.z >> 9], 1u);
            atomicAdd(&hr[r4.w >> 9], 1u);
            atomicAdd(&hc[c4.x >> 9], 1u);
            atomicAdd(&hc[c4.y >> 9], 1u);
            atomicAdd(&hc[c4.z >> 9], 1u);
            atomicAdd(&hc[c4.w >> 9], 1u);
            int u0 = ucnt[r4.x], u1 = ucnt[r4.y], u2 = ucnt[r4.z], u3 = ucnt[r4.w];
            if (u0 > 0) { int i = atomicAdd(&lcnt, 1); if (i < 256) buf[i] = make_int2(c4.x, u0); }
            if (u1 > 0) { int i = atomicAdd(&lcnt, 1); if (i < 256) buf[i] = make_int2(c4.y, u1); }
            if (u2 > 0) { int i = atomicAdd(&lcnt, 1); if (i < 256) buf[i] = make_int2(c4.z, u2); }
            if (u3 > 0) { int i = atomicAdd(&lcnt, 1); if (i < 256) buf[i] = make_int2(c4.w, u3); }
        } else {
            for (int e = base; e < e1; ++e) {
                int r = row[e], c = col[e];
                atomicAdd(&hr[r >> 9], 1u);
                atomicAdd(&hc[c >> 9], 1u);
                int u = ucnt[r];
                if (u > 0) { int i = atomicAdd(&lcnt, 1); if (i < 256) buf[i] = make_int2(c, u); }
            }
        }
    }
    __syncthreads();
    for (int i = t; i < NBUK; i += 512) {
        cntR[(size_t)blk * NBUK + i] = (unsigned short)hr[i];
        cntC[(size_t)blk * NBUK + i] = (unsigned short)hc[i];
    }
    if (t == 0) {
        int c = lcnt; c = c < 256 ? c : 256;
        lbase = atomicAdd(n_sel, c);
    }
    __syncthreads();
    int c = lcnt; c = c < 256 ? c : 256;
    int b = lbase;
    for (int i = t; i < c; i += 512) {
        int o = b + i;
        if (o < SEL_CAP) { sel_col[o] = buf[i].x; sel_w[o] = (float)buf[i].y; }
    }
}

// ---- stage 2: per-bucket prefix over 1024 slices (2 slices/thread) -------

__global__ __launch_bounds__(512) void bprefix1_kernel(
        const unsigned short* __restrict__ cntR, const unsigned short* __restrict__ cntC,
        unsigned short* __restrict__ offR, unsigned short* __restrict__ offC,
        int* __restrict__ totRC) {
    int side = blockIdx.x / NBUK;
    int b = blockIdx.x - side * NBUK;
    const unsigned short* cnt = side ? cntC : cntR;
    unsigned short* off = side ? offC : offR;
    __shared__ int sm[512];
    int t = threadIdx.x;
    int v0 = (int)cnt[(size_t)(2 * t) * NBUK + b];
    int v1 = (int)cnt[(size_t)(2 * t + 1) * NBUK + b];
    int p = v0 + v1;
    sm[t] = p;
    __syncthreads();
    for (int o = 1; o < 512; o <<= 1) {
        int x = (t >= o) ? sm[t - o] : 0;
        __syncthreads();
        sm[t] += x;
        __syncthreads();
    }
    int excl = sm[t] - p;
    off[(size_t)(2 * t) * NBUK + b]     = (unsigned short)excl;
    off[(size_t)(2 * t + 1) * NBUK + b] = (unsigned short)(excl + v0);
    if (t == 511) totRC[side * NBUK + b] = sm[511];
}

__global__ __launch_bounds__(512) void bprefix2_kernel(
        const int* __restrict__ totRC, int* __restrict__ baseR, int* __restrict__ baseC) {
    const int* tot = totRC + blockIdx.x * NBUK;
    int* base = blockIdx.x ? baseC : baseR;
    __shared__ int sm[512];
    int t = threadIdx.x;
    int v = (t < NBUK) ? tot[t] : 0;
    sm[t] = v;
    __syncthreads();
    for (int o = 1; o < 512; o <<= 1) {
        int x = (t >= o) ? sm[t - o] : 0;
        __syncthreads();
        sm[t] += x;
        __syncthreads();
    }
    if (t < NBUK) base[t] = sm[t] - v;
    if (t == NBUK - 1) base[NBUK] = sm[t];     // == NEDGE
}

// ---- stage 3: placement -- in-place ranking, LDS sort, flat write-out ----

__global__ __launch_bounds__(512) void place_kernel(
        const int* __restrict__ row, const int* __restrict__ col,
        const unsigned short* __restrict__ cntR, const unsigned short* __restrict__ cntC,
        const unsigned short* __restrict__ offR, const unsigned short* __restrict__ offC,
        const int* __restrict__ baseR, const int* __restrict__ baseC,
        unsigned short* __restrict__ midR, unsigned int* __restrict__ midC) {
    __shared__ int lofC[NBUK], lofR[NBUK], posC[NBUK], posR[NBUK];
    __shared__ int cCl[NBUK], cRl[NBUK];
    __shared__ unsigned int hrP[NBUK], hcP[NBUK];   // rank counters
    __shared__ int scan_tmp[512];
    __shared__ unsigned int   stC[EPS];
    __shared__ unsigned short stR[EPS];
    __shared__ unsigned short bmapC[EPS], bmapR[EPS];
    int blk = blockIdx.x, t = threadIdx.x;
    if (t < NBUK) {
        cCl[t] = (int)cntC[(size_t)blk * NBUK + t];
        cRl[t] = (int)cntR[(size_t)blk * NBUK + t];
        posC[t] = baseC[t] + (int)offC[(size_t)blk * NBUK + t];
        posR[t] = baseR[t] + (int)offR[(size_t)blk * NBUK + t];
    }
    __syncthreads();
    scan_tmp[t] = (t < NBUK) ? cCl[t] : 0;
    __syncthreads();
    for (int o = 1; o < 512; o <<= 1) {
        int v = (t >= o) ? scan_tmp[t - o] : 0;
        __syncthreads();
        scan_tmp[t] += v;
        __syncthreads();
    }
    if (t < NBUK) lofC[t] = scan_tmp[t] - cCl[t];
    __syncthreads();
    scan_tmp[t] = (t < NBUK) ? cRl[t] : 0;
    __syncthreads();
    for (int o = 1; o < 512; o <<= 1) {
        int v = (t >= o) ? scan_tmp[t - o] : 0;
        __syncthreads();
        scan_tmp[t] += v;
        __syncthreads();
    }
    if (t < NBUK) lofR[t] = scan_tmp[t] - cRl[t];
    __syncthreads();
    // j -> bucket maps (st* are bucket-contiguous) + zero rank counters
    if (t < NBUK) {
        int c = cCl[t], lo = lofC[t];
        for (int k = 0; k < c; ++k) bmapC[lo + k] = (unsigned short)t;
        c = cRl[t]; lo = lofR[t];
        for (int k = 0; k < c; ++k) bmapR[lo + k] = (unsigned short)t;
    }
    for (int i = t; i < NBUK; i += 512) { hrP[i] = 0; hcP[i] = 0; }
    __syncthreads();
    int e0 = blk * EPS;
    int e1 = e0 + EPS; if (e1 > NEDGE) e1 = NEDGE;
    for (int base = e0 + t * 4; base < e1; base += 2048) {
        if (base + 4 <= e1) {
            int4 r4 = *(const int4*)(row + base);
            int4 c4 = *(const int4*)(col + base);
            unsigned int kc0 = atomicAdd(&hcP[c4.x >> 9], 1u);
            unsigned int kc1 = atomicAdd(&hcP[c4.y >> 9], 1u);
            unsigned int kc2 = atomicAdd(&hcP[c4.z >> 9], 1u);
            unsigned int kc3 = atomicAdd(&hcP[c4.w >> 9], 1u);
            stC[lofC[c4.x >> 9] + (int)kc0] = ((unsigned int)(c4.x & 511) << 18) | (unsigned int)r4.x;
            stC[lofC[c4.y >> 9] + (int)kc1] = ((unsigned int)(c4.y & 511) << 18) | (unsigned int)r4.y;
            stC[lofC[c4.z >> 9] + (int)kc2] = ((unsigned int)(c4.z & 511) << 18) | (unsigned int)r4.z;
            stC[lofC[c4.w >> 9] + (int)kc3] = ((unsigned int)(c4.w & 511) << 18) | (unsigned int)r4.w;
            unsigned int kr0 = atomicAdd(&hrP[r4.x >> 9], 1u);
            unsigned int kr1 = atomicAdd(&hrP[r4.y >> 9], 1u);
            unsigned int kr2 = atomicAdd(&hrP[r4.z >> 9], 1u);
            unsigned int kr3 = atomicAdd(&hrP[r4.w >> 9], 1u);
            stR[lofR[r4.x >> 9] + (int)kr0] = (unsigned short)(r4.x & 511);
            stR[lofR[r4.y >> 9] + (int)kr1] = (unsigned short)(r4.y & 511);
            stR[lofR[r4.z >> 9] + (int)kr2] = (unsigned short)(r4.z & 511);
            stR[lofR[r4.w >> 9] + (int)kr3] = (unsigned short)(r4.w & 511);
        } else {
            for (int e = base; e < e1; ++e) {
                int r = row[e], c = col[e];
                unsigned int kc = atomicAdd(&hcP[c >> 9], 1u);
                stC[lofC[c >> 9] + (int)kc] = ((unsigned int)(c & 511) << 18) | (unsigned int)r;
                unsigned int kr = atomicAdd(&hrP[r >> 9], 1u);
                stR[lofR[r >> 9] + (int)kr] = (unsigned short)(r & 511);
            }
        }
    }
    __syncthreads();
    // flat write-out: consecutive j -> mostly-consecutive global dst
    int total = e1 - e0;
    for (int j = t; j < total; j += 512) {
        int b = bmapC[j];
        midC[posC[b] + (j - lofC[b])] = stC[j];
        b = bmapR[j];
        midR[posR[b] + (j - lofR[b])] = stR[j];
    }
}

// ---- stage 4 (fused): col CSR + row deg/dinv + embed->bf16 y0 ------------

__global__ __launch_bounds__(1024) void bfinal_kernel(
        const unsigned int* __restrict__ midC, const int* __restrict__ baseC,
        const unsigned short* __restrict__ midR, const int* __restrict__ baseR,
        const float4* __restrict__ embed,
        int* __restrict__ rptr, int* __restrict__ src_sorted,
        float* __restrict__ dinv, float* __restrict__ dinv2,
        uint2* __restrict__ y0) {
    __shared__ int cnt[512], sm[512], cur[512];
    __shared__ float dinvL[512];
    int b = blockIdx.x, t = threadIdx.x;
    // --- col part ---
    int s0 = baseC[b], s1 = baseC[b + 1];
    if (t < 512) cnt[t] = 0;
    __syncthreads();
    for (int i = s0 + t; i < s1; i += 1024) atomicAdd(&cnt[midC[i] >> 18], 1);
    __syncthreads();
    if (t < 512) sm[t] = cnt[t];
    __syncthreads();
    for (int off = 1; off < 512; off <<= 1) {
        int v = 0;
        if (t < 512 && t >= off) v = sm[t - off];
        __syncthreads();
        if (t < 512) sm[t] += v;
        __syncthreads();
    }
    if (t < 512) {
        int excl = s0 + sm[t] - cnt[t];
        int n = b * 512 + t;
        if (n < NNODES) rptr[n] = excl;
        cur[t] = excl;
    }
    if (b == NBUK - 1 && t == 0) rptr[NNODES] = s1;   // == NEDGE
    if (b == 0 && t < 16) y0[(size_t)NNODES * 16 + t] = make_uint2(0u, 0u); // sentinel zero row
    __syncthreads();
    for (int i = s0 + t; i < s1; i += 1024) {
        unsigned int v = midC[i];
        int dst = atomicAdd(&cur[v >> 18], 1);
        src_sorted[dst] = (int)(v & 0x3FFFFu);
    }
    __syncthreads();
    // --- row part ---
    if (t < 512) cnt[t] = 0;
    __syncthreads();
    int r0 = baseR[b], r1 = baseR[b + 1];
    for (int i = r0 + t; i < r1; i += 1024) atomicAdd(&cnt[midR[i]], 1);
    __syncthreads();
    if (t < 512) {
        int n = b * 512 + t;
        if (n < NNODES) {
            float d = fmaxf((float)cnt[t], 1.0f);
            float di = rsqrtf(d);
            dinv[n] = di; dinv2[n] = 1.0f / d;
            dinvL[t] = di;
        }
    }
    __syncthreads();
    // --- cvt part: y0 = bf16(dinv * embed) for this node range ---
    int nbase = b * 512;
    int nmax = NNODES - nbase; if (nmax > 512) nmax = 512;
    if (nmax < 0) nmax = 0;
    for (int i = t; i < nmax * 16; i += 1024) {
        int ln = i >> 4, slot = i & 15;
        float d = dinvL[ln];
        float4 v = embed[(size_t)(nbase + ln) * 16 + slot];
        unsigned int w0 = (unsigned int)f2bf(v.x * d) | ((unsigned int)f2bf(v.y * d) << 16);
        unsigned int w1 = (unsigned int)f2bf(v.z * d) | ((unsigned int)f2bf(v.w * d) << 16);
        y0[(size_t)(nbase + ln) * 16 + slot] = make_uint2(w0, w1);
    }
}

// ---- propagation: 8 lanes/node, uint4 (8 bf16)/lane; src-prefetch pipeline,
//      parallel sentinel tail (node NNODES is an always-zero row) -----------

#define ACC8(V) do { \
    a0 += __uint_as_float((V).x << 16); a1 += __uint_as_float((V).x & 0xffff0000u); \
    a2 += __uint_as_float((V).y << 16); a3 += __uint_as_float((V).y & 0xffff0000u); \
    a4 += __uint_as_float((V).z << 16); a5 += __uint_as_float((V).z & 0xffff0000u); \
    a6 += __uint_as_float((V).w << 16); a7 += __uint_as_float((V).w & 0xffff0000u); \
} while (0)

// shared gather body: accumulate neighbors of `node`, write x_out row
__device__ __forceinline__ void prop_node(
        const uint4* __restrict__ x_in, uint4* __restrict__ x_out,
        const int* __restrict__ ptr, const int* __restrict__ src,
        const float* __restrict__ scale, int node, int sl) {
    int i = ptr[node], e = ptr[node + 1];
    float sc = scale[node];
    float a0 = 0.f, a1 = 0.f, a2 = 0.f, a3 = 0.f;
    float a4 = 0.f, a5 = 0.f, a6 = 0.f, a7 = 0.f;
    int p0, p1, p2, p3;
    if (i + 4 <= e) { p0 = src[i]; p1 = src[i + 1]; p2 = src[i + 2]; p3 = src[i + 3]; }
    while (i + 8 <= e) {
        uint4 w0 = x_in[p0 * 8 + sl];
        uint4 w1 = x_in[p1 * 8 + sl];
        uint4 w2 = x_in[p2 * 8 + sl];
        uint4 w3 = x_in[p3 * 8 + sl];
        p0 = src[i + 4]; p1 = src[i + 5]; p2 = src[i + 6]; p3 = src[i + 7];
        i += 4;
        ACC8(w0); ACC8(w1); ACC8(w2); ACC8(w3);
    }
    if (i + 4 <= e) {
        uint4 w0 = x_in[p0 * 8 + sl];
        uint4 w1 = x_in[p1 * 8 + sl];
        uint4 w2 = x_in[p2 * 8 + sl];
        uint4 w3 = x_in[p3 * 8 + sl];
        i += 4;
        ACC8(w0); ACC8(w1); ACC8(w2); ACC8(w3);
    }
    if (i < e) {               // tail 1..3: clamp to sentinel zero row
        int q0 = src[i];
        int q1 = (i + 1 < e) ? src[i + 1] : NNODES;
        int q2 = (i + 2 < e) ? src[i + 2] : NNODES;
        uint4 w0 = x_in[q0 * 8 + sl];
        uint4 w1 = x_in[q1 * 8 + sl];
        uint4 w2 = x_in[q2 * 8 + sl];
        ACC8(w0); ACC8(w1); ACC8(w2);
    }
    uint4 o;
    o.x = (unsigned int)f2bf(a0 * sc) | ((unsigned int)f2bf(a1 * sc) << 16);
    o.y = (unsigned int)f2bf(a2 * sc) | ((unsigned int)f2bf(a3 * sc) << 16);
    o.z = (unsigned int)f2bf(a4 * sc) | ((unsigned int)f2bf(a5 * sc) << 16);
    o.w = (unsigned int)f2bf(a6 * sc) | ((unsigned int)f2bf(a7 * sc) << 16);
    x_out[(size_t)node * 8 + sl] = o;
}

__global__ __launch_bounds__(256, 8) void prop_kernel(
        const uint4* __restrict__ x_in, uint4* __restrict__ x_out,
        const int* __restrict__ ptr, const int* __restrict__ src,
        const float* __restrict__ scale) {
    int gid  = blockIdx.x * blockDim.x + threadIdx.x;
    int node = gid >> 3;       // 8 lanes per node
    int sl   = gid & 7;        // lane's 8-dim slot within the row
    if (node > NNODES) return;
    if (node == NNODES) {      // keep sentinel row zero for next layer
        x_out[(size_t)node * 8 + sl] = make_uint4(0u, 0u, 0u, 0u);
        return;
    }
    prop_node(x_in, x_out, ptr, src, scale, node, sl);
}

// layer 3: only nodes consumed downstream — users, items+NUM_USERS, sel_col.
// Grid-stride over the actual list length (no SEL_CAP block drain).
__global__ __launch_bounds__(256, 8) void prop_list_kernel(
        const uint4* __restrict__ x_in, uint4* __restrict__ x_out,
        const int* __restrict__ ptr, const int* __restrict__ src,
        const float* __restrict__ scale,
        const int* __restrict__ users, const int* __restrict__ items,
        const int* __restrict__ sel_col, const int* __restrict__ n_sel_p) {
    int n = *n_sel_p; if (n > SEL_CAP) n = SEL_CAP;
    int total = (2 * BATCH + n) * 8;
    int nth = gridDim.x * blockDim.x;
    for (int gid = blockIdx.x * blockDim.x + threadIdx.x; gid < total; gid += nth) {
        int li = gid >> 3;
        int sl = gid & 7;
        int node;
        if (li < BATCH) {
            node = users[li];
        } else if (li < 2 * BATCH) {
            node = items[li - BATCH] + NUM_USERS;
        } else {
            node = sel_col[li - 2 * BATCH];
        }
        prop_node(x_in, x_out, ptr, src, scale, node, sl);
    }
}

// ---- batch / softmax part (x is bf16) -----------------------------------

__global__ void ucnt_kernel(const int* __restrict__ users, int* __restrict__ ucnt) {
    int b = blockIdx.x * blockDim.x + threadIdx.x;
    if (b < BATCH) atomicAdd(&ucnt[users[b]], 1);
}

// 64 blocks x 16 users; one atomicAdd per lane into zeroed ctx (raw sum).
__global__ __launch_bounds__(256) void ctx_part_kernel(
        const unsigned short* __restrict__ x, const int* __restrict__ users,
        float* __restrict__ ctx) {
    __shared__ float sm[256];
    int lane = threadIdx.x & 63, wl = threadIdx.x >> 6;
    int b0 = blockIdx.x * 16 + wl * 4;
    float acc = 0.0f;
    #pragma unroll
    for (int k = 0; k < 4; ++k)
        acc += bf2f(x[users[b0 + k] * DIM + lane]);
    sm[threadIdx.x] = acc;
    __syncthreads();
    if (wl == 0)
        atomicAdd(&ctx[lane], sm[lane] + sm[64 + lane] + sm[128 + lane] + sm[192 + lane]);
}

__global__ void softmax_kernel(const unsigned short* __restrict__ x,
                               const float* __restrict__ ctx,
                               const int* __restrict__ sel_col,
                               const float* __restrict__ sel_w,
                               const int* __restrict__ n_sel_p,
                               float* __restrict__ S, float* __restrict__ zp) {
    __shared__ float smS[4 * 64];
    __shared__ float smZ[4];
    int lane = threadIdx.x & 63, wl = threadIdx.x >> 6;
    int n = *n_sel_p; if (n > SEL_CAP) n = SEL_CAP;
    float c = ctx[lane] * (1.0f / BATCH);   // ctx holds raw sum over users
    float accS = 0.0f, accZ = 0.0f;
    int stride = gridDim.x * 4;
    for (int idx = blockIdx.x * 4 + wl; idx < n; idx += stride) {
        int node = sel_col[idx];
        float xv = bf2f(x[node * DIM + lane]);
        float v = wave_sum64(xv * c);
        float w = sel_w[idx] * __expf(v);
        accS = fmaf(w, xv, accS);
        accZ += w;
    }
    smS[wl * 64 + lane] = accS;
    if (lane == 0) smZ[wl] = accZ;
    __syncthreads();
    if (wl == 0) {
        float s = smS[lane] + smS[64 + lane] + smS[128 + lane] + smS[192 + lane];
        atomicAdd(&S[lane], s);
    }
    if (threadIdx.x == 0) atomicAdd(zp, smZ[0] + smZ[1] + smZ[2] + smZ[3]);
}

__global__ void score_kernel(const unsigned short* __restrict__ x, const int* __restrict__ users,
                             const int* __restrict__ items, const float* __restrict__ S,
                             const float* __restrict__ zp, float* __restrict__ out) {
    int gid = blockIdx.x * blockDim.x + threadIdx.x;
    int b = gid >> 6, lane = gid & 63;
    if (b >= BATCH) return;
    float z = fmaxf(*zp, 1e-12f);
    float na = S[lane] / z;
    int u = users[b], it = items[b] + NUM_USERS;
    float v = bf2f(x[u * DIM + lane]) * (bf2f(x[it * DIM + lane]) + na);
    v = wave_sum64(v);
    if (lane == 0) out[b] = 1.0f / (1.0f + __expf(-v));
}

// ---- launch -------------------------------------------------------------

extern "C" void kernel_launch(void* const* d_in, const int* in_sizes, int n_in,
                              void* d_out, int out_size, void* d_ws, size_t ws_size,
                              hipStream_t stream) {
    const float* embed = (const float*)d_in[0];
    const int*   edge  = (const int*)d_in[1];
    const int*   row   = edge;
    const int*   col   = edge + NEDGE;
    const int*   users = (const int*)d_in[2];
    const int*   items = (const int*)d_in[3];
    float*       out   = (float*)d_out;
    char*        ws    = (char*)d_ws;

    size_t off = 0;
    auto A = [&](size_t bytes) { size_t o = off; off += (bytes + 255) & ~(size_t)255; return o; };
    size_t o_mid   = A((size_t)NEDGE * 4 + (size_t)NEDGE * 2);  // midC 8MB + midR 4MB
    size_t o_xa    = A((size_t)(NNODES + 1) * DIM * 2);     // +1: sentinel zero row
    size_t o_xb    = A((size_t)(NNODES + 1) * DIM * 2);
    size_t o_src   = A((size_t)NEDGE * 4);             // 8 MB, alive thru prop
    size_t o_cntR  = A((size_t)SLICES * NBUK * 2);     // 600 KB
    size_t o_cntC  = A((size_t)SLICES * NBUK * 2);
    size_t o_offR  = A((size_t)SLICES * NBUK * 2);
    size_t o_offC  = A((size_t)SLICES * NBUK * 2);
    size_t o_tot   = A((size_t)2 * NBUK * 4);
    size_t o_baseR = A((size_t)(NBUK + 1) * 4);
    size_t o_baseC = A((size_t)(NBUK + 1) * 4);
    size_t o_selc  = A((size_t)SEL_CAP * 4);
    size_t o_selw  = A((size_t)SEL_CAP * 4);
    size_t o_zero  = off;                              // ---- zeroed block ----
    size_t o_ucnt  = A((size_t)NNODES * 4);
    size_t o_misc  = A(1024);                          // n_sel@0, z@8, S@256, ctx@512
    size_t zero_bytes = off - o_zero;                  // ---- end zero -------
    size_t o_dinv  = A((size_t)NNODES * 4);
    size_t o_dinv2 = A((size_t)NNODES * 4);
    size_t o_rptr  = A((size_t)(NNODES + 1) * 4);

    unsigned int*   midC = (unsigned int*)(ws + o_mid);
    unsigned short* midR = (unsigned short*)(ws + o_mid + (size_t)NEDGE * 4);
    unsigned short* xa   = (unsigned short*)(ws + o_xa);
    unsigned short* xb   = (unsigned short*)(ws + o_xb);
    int*   srcS  = (int*)(ws + o_src);
    unsigned short* cntR = (unsigned short*)(ws + o_cntR);
    unsigned short* cntC = (unsigned short*)(ws + o_cntC);
    unsigned short* offR = (unsigned short*)(ws + o_offR);
    unsigned short* offC = (unsigned short*)(ws + o_offC);
    int*   totRC = (int*)(ws + o_tot);
    int*   baseR = (int*)(ws + o_baseR);
    int*   baseC = (int*)(ws + o_baseC);
    int*   selc  = (int*)(ws + o_selc);
    float* selw  = (float*)(ws + o_selw);
    int*   ucnt  = (int*)(ws + o_ucnt);
    int*   nsel  = (int*)(ws + o_misc);
    float* zp    = (float*)(ws + o_misc + 8);
    float* S     = (float*)(ws + o_misc + 256);
    float* ctx   = (float*)(ws + o_misc + 512);
    float* dinv  = (float*)(ws + o_dinv);
    float* dinv2 = (float*)(ws + o_dinv2);
    int*   rptr  = (int*)(ws + o_rptr);

    hipMemsetAsync(ws + o_zero, 0, zero_bytes, stream);

    ucnt_kernel<<<(BATCH + 255) / 256, 256, 0, stream>>>(users, ucnt);

    // atomic-free CSR build (selection fused into bhist; ranks computed in place)
    bhist_kernel<<<SLICES, 512, 0, stream>>>(row, col, ucnt, cntR, cntC,
                                             nsel, selc, selw);
    bprefix1_kernel<<<2 * NBUK, 512, 0, stream>>>(cntR, cntC, offR, offC, totRC);
    bprefix2_kernel<<<2, 512, 0, stream>>>(totRC, baseR, baseC);
    place_kernel<<<SLICES, 512, 0, stream>>>(row, col, cntR, cntC,
                                             offR, offC, baseR, baseC, midR, midC);
    // fused: col CSR + row deg + embed->y0 conversion
    bfinal_kernel<<<NBUK, 1024, 0, stream>>>(midC, baseC, midR, baseR,
                                             (const float4*)embed, rptr, srcS,
                                             dinv, dinv2, (uint2*)xa);

    // layers 1,2 full: y->y (dinv2), y->y (dinv2); layer 3 selective: y->x (dinv)
    int prop_blocks = ((NNODES + 1) * 8 + 255) / 256;
    prop_kernel<<<prop_blocks, 256, 0, stream>>>((const uint4*)xa, (uint4*)xb, rptr, srcS, dinv2);
    prop_kernel<<<prop_blocks, 256, 0, stream>>>((const uint4*)xb, (uint4*)xa, rptr, srcS, dinv2);
    prop_list_kernel<<<1024, 256, 0, stream>>>((const uint4*)xa, (uint4*)xb,
                                               rptr, srcS, dinv,
                                               users, items, selc, nsel);
    // final x rows (users/items/sel) live in xb

    // batch softmax aggregation over selected edges (mx = 0, fused)
    ctx_part_kernel<<<64, 256, 0, stream>>>(xb, users, ctx);
    softmax_kernel<<<LOGIT_BLOCKS, 256, 0, stream>>>(xb, ctx, selc, selw, nsel, S, zp);

    // final scores
    score_kernel<<<(BATCH * 64 + 255) / 256, 256, 0, stream>>>(xb, users, items, S, zp, out);
}

// Round 7
// 261.547 us; speedup vs baseline: 1.0697x; 1.0044x over previous
//
#include <hip/hip_runtime.h>
#include <float.h>
#include <math.h>

#define NUM_USERS 100000
#define NUM_ITEMS 50000
#define NNODES    150000
#define DIM       64
#define NEDGE     2000000
#define BATCH     1024
#define SEL_CAP   (1 << 18)
#define LOGIT_BLOCKS 512

#define SLICES   1024                   // edge slices
#define EPS      1956                   // ceil(NEDGE/SLICES) rounded to x4
#define NBUK     293                    // buckets of 512 nodes (293*512=150016)
#define BCAP     8192                   // padded per-bucket capacity (exp 6826, +16 sigma)

__device__ __forceinline__ float wave_sum64(float v) {
    #pragma unroll
    for (int off = 32; off > 0; off >>= 1) v += __shfl_xor(v, off, 64);
    return v;
}

__device__ __forceinline__ float bf2f(unsigned short s) {
    return __uint_as_float(((unsigned int)s) << 16);
}
__device__ __forceinline__ unsigned short f2bf(float f) {   // RNE
    unsigned int u = __float_as_uint(f);
    return (unsigned short)((u + 0x7fffu + ((u >> 16) & 1u)) >> 16);
}

// ---- fused bucket sort: count -> chunk-reserve -> rank+scatter -----------
// Padded arenas (BCAP/bucket) remove the global prefix; chunk bases come
// from one global atomicAdd per (block,bucket). Within-bucket order is
// arbitrary (re-ranked per node in bfinal). Selection fused into pass 1.

__global__ __launch_bounds__(512) void sort_kernel(
        const int* __restrict__ row, const int* __restrict__ col,
        const int* __restrict__ ucnt,
        int* __restrict__ gcurC, int* __restrict__ gcurR,
        unsigned int* __restrict__ midC, unsigned short* __restrict__ midR,
        int* __restrict__ n_sel, int* __restrict__ sel_col, float* __restrict__ sel_w) {
    __shared__ unsigned int hr[NBUK], hc[NBUK];
    __shared__ int posC[NBUK], posR[NBUK];
    __shared__ int lcnt, lbase;
    __shared__ int2 buf[256];
    int blk = blockIdx.x, t = threadIdx.x;
    for (int i = t; i < NBUK; i += 512) { hr[i] = 0; hc[i] = 0; }
    if (t == 0) lcnt = 0;
    __syncthreads();
    int e0 = blk * EPS;
    int e1 = e0 + EPS; if (e1 > NEDGE) e1 = NEDGE;
    // pass 1: per-bucket counts + batch selection
    for (int base = e0 + t * 4; base < e1; base += 2048) {
        if (base + 4 <= e1) {
            int4 r4 = *(const int4*)(row + base);
            int4 c4 = *(const int4*)(col + base);
            atomicAdd(&hr[r4.x >> 9], 1u);
            atomicAdd(&hr[r4.y >> 9], 1u);
            atomicAdd(&hr[r4.z >> 9], 1u);
            atomicAdd(&hr[r4.w >> 9], 1u);
            atomicAdd(&hc[c4.x >> 9], 1u);
            atomicAdd(&hc[c4.y >> 9], 1u);
            atomicAdd(&hc[c4.z >> 9], 1u);
            atomicAdd(&hc[c4.w >> 9], 1u);
            int u0 = ucnt[r4.x], u1 = ucnt[r4.y], u2 = ucnt[r4.z], u3 = ucnt[r4.w];
            if (u0 > 0) { int i = atomicAdd(&lcnt, 1); if (i < 256) buf[i] = make_int2(c4.x, u0); }
            if (u1 > 0) { int i = atomicAdd(&lcnt, 1); if (i < 256) buf[i] = make_int2(c4.y, u1); }
            if (u2 > 0) { int i = atomicAdd(&lcnt, 1); if (i < 256) buf[i] = make_int2(c4.z, u2); }
            if (u3 > 0) { int i = atomicAdd(&lcnt, 1); if (i < 256) buf[i] = make_int2(c4.w, u3); }
        } else {
            for (int e = base; e < e1; ++e) {
                int r = row[e], c = col[e];
                atomicAdd(&hr[r >> 9], 1u);
                atomicAdd(&hc[c >> 9], 1u);
                int u = ucnt[r];
                if (u > 0) { int i = atomicAdd(&lcnt, 1); if (i < 256) buf[i] = make_int2(c, u); }
            }
        }
    }
    __syncthreads();
    // chunk reservation (one global atomic per bucket), then re-zero counters
    if (t < NBUK) {
        posC[t] = atomicAdd(&gcurC[t], (int)hc[t]);
        posR[t] = atomicAdd(&gcurR[t], (int)hr[t]);
        hc[t] = 0; hr[t] = 0;
    }
    __syncthreads();
    // pass 2: rank (fresh LDS atomics) + scatter write; edge re-read is L1-hot
    for (int base = e0 + t * 4; base < e1; base += 2048) {
        if (base + 4 <= e1) {
            int4 r4 = *(const int4*)(row + base);
            int4 c4 = *(const int4*)(col + base);
            int b0 = c4.x >> 9, b1 = c4.y >> 9, b2 = c4.z >> 9, b3 = c4.w >> 9;
            int k0 = posC[b0] + (int)atomicAdd(&hc[b0], 1u);
            int k1 = posC[b1] + (int)atomicAdd(&hc[b1], 1u);
            int k2 = posC[b2] + (int)atomicAdd(&hc[b2], 1u);
            int k3 = posC[b3] + (int)atomicAdd(&hc[b3], 1u);
            if (k0 < BCAP) midC[(size_t)b0 * BCAP + k0] = ((unsigned int)(c4.x & 511) << 18) | (unsigned int)r4.x;
            if (k1 < BCAP) midC[(size_t)b1 * BCAP + k1] = ((unsigned int)(c4.y & 511) << 18) | (unsigned int)r4.y;
            if (k2 < BCAP) midC[(size_t)b2 * BCAP + k2] = ((unsigned int)(c4.z & 511) << 18) | (unsigned int)r4.z;
            if (k3 < BCAP) midC[(size_t)b3 * BCAP + k3] = ((unsigned int)(c4.w & 511) << 18) | (unsigned int)r4.w;
            b0 = r4.x >> 9; b1 = r4.y >> 9; b2 = r4.z >> 9; b3 = r4.w >> 9;
            k0 = posR[b0] + (int)atomicAdd(&hr[b0], 1u);
            k1 = posR[b1] + (int)atomicAdd(&hr[b1], 1u);
            k2 = posR[b2] + (int)atomicAdd(&hr[b2], 1u);
            k3 = posR[b3] + (int)atomicAdd(&hr[b3], 1u);
            if (k0 < BCAP) midR[(size_t)b0 * BCAP + k0] = (unsigned short)(r4.x & 511);
            if (k1 < BCAP) midR[(size_t)b1 * BCAP + k1] = (unsigned short)(r4.y & 511);
            if (k2 < BCAP) midR[(size_t)b2 * BCAP + k2] = (unsigned short)(r4.z & 511);
            if (k3 < BCAP) midR[(size_t)b3 * BCAP + k3] = (unsigned short)(r4.w & 511);
        } else {
            for (int e = base; e < e1; ++e) {
                int r = row[e], c = col[e];
                int bc = c >> 9;
                int kc = posC[bc] + (int)atomicAdd(&hc[bc], 1u);
                if (kc < BCAP) midC[(size_t)bc * BCAP + kc] = ((unsigned int)(c & 511) << 18) | (unsigned int)r;
                int br = r >> 9;
                int kr = posR[br] + (int)atomicAdd(&hr[br], 1u);
                if (kr < BCAP) midR[(size_t)br * BCAP + kr] = (unsigned short)(r & 511);
            }
        }
    }
    __syncthreads();
    if (t == 0) {
        int c = lcnt; c = c < 256 ? c : 256;
        lbase = atomicAdd(n_sel, c);
    }
    __syncthreads();
    int c = lcnt; c = c < 256 ? c : 256;
    int b = lbase;
    for (int i = t; i < c; i += 512) {
        int o = b + i;
        if (o < SEL_CAP) { sel_col[o] = buf[i].x; sel_w[o] = (float)buf[i].y; }
    }
}

// ---- stage 2 (fused): col CSR + row deg/dinv + embed->bf16 y0 ------------

__global__ __launch_bounds__(1024) void bfinal_kernel(
        const unsigned int* __restrict__ midC, const int* __restrict__ gcurC,
        const unsigned short* __restrict__ midR, const int* __restrict__ gcurR,
        const float4* __restrict__ embed,
        int* __restrict__ rptr, int* __restrict__ rend, int* __restrict__ src_sorted,
        float* __restrict__ dinv, float* __restrict__ dinv2,
        uint2* __restrict__ y0) {
    __shared__ int cnt[512], sm[512], cur[512];
    __shared__ float dinvL[512];
    int b = blockIdx.x, t = threadIdx.x;
    // --- col part ---
    int s0 = b * BCAP;
    int cc = gcurC[b]; if (cc > BCAP) cc = BCAP;
    int s1 = s0 + cc;
    if (t < 512) cnt[t] = 0;
    __syncthreads();
    for (int i = s0 + t; i < s1; i += 1024) atomicAdd(&cnt[midC[i] >> 18], 1);
    __syncthreads();
    if (t < 512) sm[t] = cnt[t];
    __syncthreads();
    for (int off = 1; off < 512; off <<= 1) {
        int v = 0;
        if (t < 512 && t >= off) v = sm[t - off];
        __syncthreads();
        if (t < 512) sm[t] += v;
        __syncthreads();
    }
    if (t < 512) {
        int excl = s0 + sm[t] - cnt[t];
        int n = b * 512 + t;
        if (n < NNODES) { rptr[n] = excl; rend[n] = s0 + sm[t]; }
        cur[t] = excl;
    }
    if (b == 0 && t < 16) y0[(size_t)NNODES * 16 + t] = make_uint2(0u, 0u); // sentinel zero row
    __syncthreads();
    for (int i = s0 + t; i < s1; i += 1024) {
        unsigned int v = midC[i];
        int dst = atomicAdd(&cur[v >> 18], 1);
        src_sorted[dst] = (int)(v & 0x3FFFFu);
    }
    __syncthreads();
    // --- row part (deg) ---
    if (t < 512) cnt[t] = 0;
    __syncthreads();
    int r0 = b * BCAP;
    int rc = gcurR[b]; if (rc > BCAP) rc = BCAP;
    int r1 = r0 + rc;
    for (int i = r0 + t; i < r1; i += 1024) atomicAdd(&cnt[midR[i]], 1);
    __syncthreads();
    if (t < 512) {
        int n = b * 512 + t;
        if (n < NNODES) {
            float d = fmaxf((float)cnt[t], 1.0f);
            float di = rsqrtf(d);
            dinv[n] = di; dinv2[n] = 1.0f / d;
            dinvL[t] = di;
        }
    }
    __syncthreads();
    // --- cvt part: y0 = bf16(dinv * embed) for this node range ---
    int nbase = b * 512;
    int nmax = NNODES - nbase; if (nmax > 512) nmax = 512;
    if (nmax < 0) nmax = 0;
    for (int i = t; i < nmax * 16; i += 1024) {
        int ln = i >> 4, slot = i & 15;
        float d = dinvL[ln];
        float4 v = embed[(size_t)(nbase + ln) * 16 + slot];
        unsigned int w0 = (unsigned int)f2bf(v.x * d) | ((unsigned int)f2bf(v.y * d) << 16);
        unsigned int w1 = (unsigned int)f2bf(v.z * d) | ((unsigned int)f2bf(v.w * d) << 16);
        y0[(size_t)(nbase + ln) * 16 + slot] = make_uint2(w0, w1);
    }
}

// ---- propagation: 8 lanes/node, uint4 (8 bf16)/lane; src-prefetch pipeline,
//      parallel sentinel tail (node NNODES is an always-zero row) -----------

#define ACC8(V) do { \
    a0 += __uint_as_float((V).x << 16); a1 += __uint_as_float((V).x & 0xffff0000u); \
    a2 += __uint_as_float((V).y << 16); a3 += __uint_as_float((V).y & 0xffff0000u); \
    a4 += __uint_as_float((V).z << 16); a5 += __uint_as_float((V).z & 0xffff0000u); \
    a6 += __uint_as_float((V).w << 16); a7 += __uint_as_float((V).w & 0xffff0000u); \
} while (0)

// shared gather body: accumulate neighbors of `node`, write x_out row
__device__ __forceinline__ void prop_node(
        const uint4* __restrict__ x_in, uint4* __restrict__ x_out,
        const int* __restrict__ ptr, const int* __restrict__ rend,
        const int* __restrict__ src,
        const float* __restrict__ scale, int node, int sl) {
    int i = ptr[node], e = rend[node];
    float sc = scale[node];
    float a0 = 0.f, a1 = 0.f, a2 = 0.f, a3 = 0.f;
    float a4 = 0.f, a5 = 0.f, a6 = 0.f, a7 = 0.f;
    int p0, p1, p2, p3;
    if (i + 4 <= e) { p0 = src[i]; p1 = src[i + 1]; p2 = src[i + 2]; p3 = src[i + 3]; }
    while (i + 8 <= e) {
        uint4 w0 = x_in[p0 * 8 + sl];
        uint4 w1 = x_in[p1 * 8 + sl];
        uint4 w2 = x_in[p2 * 8 + sl];
        uint4 w3 = x_in[p3 * 8 + sl];
        p0 = src[i + 4]; p1 = src[i + 5]; p2 = src[i + 6]; p3 = src[i + 7];
        i += 4;
        ACC8(w0); ACC8(w1); ACC8(w2); ACC8(w3);
    }
    if (i + 4 <= e) {
        uint4 w0 = x_in[p0 * 8 + sl];
        uint4 w1 = x_in[p1 * 8 + sl];
        uint4 w2 = x_in[p2 * 8 + sl];
        uint4 w3 = x_in[p3 * 8 + sl];
        i += 4;
        ACC8(w0); ACC8(w1); ACC8(w2); ACC8(w3);
    }
    if (i < e) {               // tail 1..3: clamp to sentinel zero row
        int q0 = src[i];
        int q1 = (i + 1 < e) ? src[i + 1] : NNODES;
        int q2 = (i + 2 < e) ? src[i + 2] : NNODES;
        uint4 w0 = x_in[q0 * 8 + sl];
        uint4 w1 = x_in[q1 * 8 + sl];
        uint4 w2 = x_in[q2 * 8 + sl];
        ACC8(w0); ACC8(w1); ACC8(w2);
    }
    uint4 o;
    o.x = (unsigned int)f2bf(a0 * sc) | ((unsigned int)f2bf(a1 * sc) << 16);
    o.y = (unsigned int)f2bf(a2 * sc) | ((unsigned int)f2bf(a3 * sc) << 16);
    o.z = (unsigned int)f2bf(a4 * sc) | ((unsigned int)f2bf(a5 * sc) << 16);
    o.w = (unsigned int)f2bf(a6 * sc) | ((unsigned int)f2bf(a7 * sc) << 16);
    x_out[(size_t)node * 8 + sl] = o;
}

__global__ __launch_bounds__(256, 8) void prop_kernel(
        const uint4* __restrict__ x_in, uint4* __restrict__ x_out,
        const int* __restrict__ ptr, const int* __restrict__ rend,
        const int* __restrict__ src,
        const float* __restrict__ scale) {
    int gid  = blockIdx.x * blockDim.x + threadIdx.x;
    int node = gid >> 3;       // 8 lanes per node
    int sl   = gid & 7;        // lane's 8-dim slot within the row
    if (node > NNODES) return;
    if (node == NNODES) {      // keep sentinel row zero for next layer
        x_out[(size_t)node * 8 + sl] = make_uint4(0u, 0u, 0u, 0u);
        return;
    }
    prop_node(x_in, x_out, ptr, rend, src, scale, node, sl);
}

// layer 3: only nodes consumed downstream — users, items+NUM_USERS, sel_col.
__global__ __launch_bounds__(256, 8) void prop_list_kernel(
        const uint4* __restrict__ x_in, uint4* __restrict__ x_out,
        const int* __restrict__ ptr, const int* __restrict__ rend,
        const int* __restrict__ src,
        const float* __restrict__ scale,
        const int* __restrict__ users, const int* __restrict__ items,
        const int* __restrict__ sel_col, const int* __restrict__ n_sel_p) {
    int n = *n_sel_p; if (n > SEL_CAP) n = SEL_CAP;
    int total = (2 * BATCH + n) * 8;
    int nth = gridDim.x * blockDim.x;
    for (int gid = blockIdx.x * blockDim.x + threadIdx.x; gid < total; gid += nth) {
        int li = gid >> 3;
        int sl = gid & 7;
        int node;
        if (li < BATCH) {
            node = users[li];
        } else if (li < 2 * BATCH) {
            node = items[li - BATCH] + NUM_USERS;
        } else {
            node = sel_col[li - 2 * BATCH];
        }
        prop_node(x_in, x_out, ptr, rend, src, scale, node, sl);
    }
}

// ---- batch / softmax part (x is bf16) -----------------------------------

__global__ void ucnt_kernel(const int* __restrict__ users, int* __restrict__ ucnt) {
    int b = blockIdx.x * blockDim.x + threadIdx.x;
    if (b < BATCH) atomicAdd(&ucnt[users[b]], 1);
}

// 64 blocks x 16 users; one atomicAdd per lane into zeroed ctx (raw sum).
__global__ __launch_bounds__(256) void ctx_part_kernel(
        const unsigned short* __restrict__ x, const int* __restrict__ users,
        float* __restrict__ ctx) {
    __shared__ float sm[256];
    int lane = threadIdx.x & 63, wl = threadIdx.x >> 6;
    int b0 = blockIdx.x * 16 + wl * 4;
    float acc = 0.0f;
    #pragma unroll
    for (int k = 0; k < 4; ++k)
        acc += bf2f(x[users[b0 + k] * DIM + lane]);
    sm[threadIdx.x] = acc;
    __syncthreads();
    if (wl == 0)
        atomicAdd(&ctx[lane], sm[lane] + sm[64 + lane] + sm[128 + lane] + sm[192 + lane]);
}

__global__ void softmax_kernel(const unsigned short* __restrict__ x,
                               const float* __restrict__ ctx,
                               const int* __restrict__ sel_col,
                               const float* __restrict__ sel_w,
                               const int* __restrict__ n_sel_p,
                               float* __restrict__ S, float* __restrict__ zp) {
    __shared__ float smS[4 * 64];
    __shared__ float smZ[4];
    int lane = threadIdx.x & 63, wl = threadIdx.x >> 6;
    int n = *n_sel_p; if (n > SEL_CAP) n = SEL_CAP;
    float c = ctx[lane] * (1.0f / BATCH);   // ctx holds raw sum over users
    float accS = 0.0f, accZ = 0.0f;
    int stride = gridDim.x * 4;
    for (int idx = blockIdx.x * 4 + wl; idx < n; idx += stride) {
        int node = sel_col[idx];
        float xv = bf2f(x[node * DIM + lane]);
        float v = wave_sum64(xv * c);
        float w = sel_w[idx] * __expf(v);
        accS = fmaf(w, xv, accS);
        accZ += w;
    }
    smS[wl * 64 + lane] = accS;
    if (lane == 0) smZ[wl] = accZ;
    __syncthreads();
    if (wl == 0) {
        float s = smS[lane] + smS[64 + lane] + smS[128 + lane] + smS[192 + lane];
        atomicAdd(&S[lane], s);
    }
    if (threadIdx.x == 0) atomicAdd(zp, smZ[0] + smZ[1] + smZ[2] + smZ[3]);
}

__global__ void score_kernel(const unsigned short* __restrict__ x, const int* __restrict__ users,
                             const int* __restrict__ items, const float* __restrict__ S,
                             const float* __restrict__ zp, float* __restrict__ out) {
    int gid = blockIdx.x * blockDim.x + threadIdx.x;
    int b = gid >> 6, lane = gid & 63;
    if (b >= BATCH) return;
    float z = fmaxf(*zp, 1e-12f);
    float na = S[lane] / z;
    int u = users[b], it = items[b] + NUM_USERS;
    float v = bf2f(x[u * DIM + lane]) * (bf2f(x[it * DIM + lane]) + na);
    v = wave_sum64(v);
    if (lane == 0) out[b] = 1.0f / (1.0f + __expf(-v));
}

// ---- launch -------------------------------------------------------------

extern "C" void kernel_launch(void* const* d_in, const int* in_sizes, int n_in,
                              void* d_out, int out_size, void* d_ws, size_t ws_size,
                              hipStream_t stream) {
    const float* embed = (const float*)d_in[0];
    const int*   edge  = (const int*)d_in[1];
    const int*   row   = edge;
    const int*   col   = edge + NEDGE;
    const int*   users = (const int*)d_in[2];
    const int*   items = (const int*)d_in[3];
    float*       out   = (float*)d_out;
    char*        ws    = (char*)d_ws;

    size_t off = 0;
    auto A = [&](size_t bytes) { size_t o = off; off += (bytes + 255) & ~(size_t)255; return o; };
    size_t o_midC  = A((size_t)NBUK * BCAP * 4);            // 9.6 MB padded
    size_t o_midR  = A((size_t)NBUK * BCAP * 2);            // 4.8 MB padded
    size_t o_xa    = A((size_t)(NNODES + 1) * DIM * 2);     // +1: sentinel zero row
    size_t o_xb    = A((size_t)(NNODES + 1) * DIM * 2);
    size_t o_src   = A((size_t)NBUK * BCAP * 4);            // 9.6 MB padded, alive thru prop
    size_t o_selc  = A((size_t)SEL_CAP * 4);
    size_t o_selw  = A((size_t)SEL_CAP * 4);
    size_t o_zero  = off;                                   // ---- zeroed block ----
    size_t o_ucnt  = A((size_t)NNODES * 4);
    size_t o_gcurC = A((size_t)NBUK * 4);
    size_t o_gcurR = A((size_t)NBUK * 4);
    size_t o_misc  = A(1024);                               // n_sel@0, z@8, S@256, ctx@512
    size_t zero_bytes = off - o_zero;                       // ---- end zero -------
    size_t o_dinv  = A((size_t)NNODES * 4);
    size_t o_dinv2 = A((size_t)NNODES * 4);
    size_t o_rptr  = A((size_t)NNODES * 4);
    size_t o_rend  = A((size_t)NNODES * 4);

    unsigned int*   midC = (unsigned int*)(ws + o_midC);
    unsigned short* midR = (unsigned short*)(ws + o_midR);
    unsigned short* xa   = (unsigned short*)(ws + o_xa);
    unsigned short* xb   = (unsigned short*)(ws + o_xb);
    int*   srcS  = (int*)(ws + o_src);
    int*   selc  = (int*)(ws + o_selc);
    float* selw  = (float*)(ws + o_selw);
    int*   ucnt  = (int*)(ws + o_ucnt);
    int*   gcurC = (int*)(ws + o_gcurC);
    int*   gcurR = (int*)(ws + o_gcurR);
    int*   nsel  = (int*)(ws + o_misc);
    float* zp    = (float*)(ws + o_misc + 8);
    float* S     = (float*)(ws + o_misc + 256);
    float* ctx   = (float*)(ws + o_misc + 512);
    float* dinv  = (float*)(ws + o_dinv);
    float* dinv2 = (float*)(ws + o_dinv2);
    int*   rptr  = (int*)(ws + o_rptr);
    int*   rend  = (int*)(ws + o_rend);

    hipMemsetAsync(ws + o_zero, 0, zero_bytes, stream);

    ucnt_kernel<<<(BATCH + 255) / 256, 256, 0, stream>>>(users, ucnt);

    // fused bucket sort (count + reserve + scatter + selection)
    sort_kernel<<<SLICES, 512, 0, stream>>>(row, col, ucnt, gcurC, gcurR,
                                            midC, midR, nsel, selc, selw);
    // fused: col CSR + row deg + embed->y0 conversion
    bfinal_kernel<<<NBUK, 1024, 0, stream>>>(midC, gcurC, midR, gcurR,
                                             (const float4*)embed, rptr, rend, srcS,
                                             dinv, dinv2, (uint2*)xa);

    // layers 1,2 full: y->y (dinv2), y->y (dinv2); layer 3 selective: y->x (dinv)
    int prop_blocks = ((NNODES + 1) * 8 + 255) / 256;
    prop_kernel<<<prop_blocks, 256, 0, stream>>>((const uint4*)xa, (uint4*)xb, rptr, rend, srcS, dinv2);
    prop_kernel<<<prop_blocks, 256, 0, stream>>>((const uint4*)xb, (uint4*)xa, rptr, rend, srcS, dinv2);
    prop_list_kernel<<<1024, 256, 0, stream>>>((const uint4*)xa, (uint4*)xb,
                                               rptr, rend, srcS, dinv,
                                               users, items, selc, nsel);
    // final x rows (users/items/sel) live in xb

    // batch softmax aggregation over selected edges (mx = 0, fused)
    ctx_part_kernel<<<64, 256, 0, stream>>>(xb, users, ctx);
    softmax_kernel<<<LOGIT_BLOCKS, 256, 0, stream>>>(xb, ctx, selc, selw, nsel, S, zp);

    // final scores
    score_kernel<<<(BATCH * 64 + 255) / 256, 256, 0, stream>>>(xb, users, items, S, zp, out);
}

// Round 8
// 258.186 us; speedup vs baseline: 1.0836x; 1.0130x over previous
//
#include <hip/hip_runtime.h>
#include <float.h>
#include <math.h>

#define NUM_USERS 100000
#define NUM_ITEMS 50000
#define NNODES    150000
#define DIM       64
#define NEDGE     2000000
#define BATCH     1024
#define SEL_CAP   (1 << 18)
#define LOGIT_BLOCKS 512

#define SLICES   1024                   // edge slices
#define EPS      1956                   // ceil(NEDGE/SLICES) rounded to x4
#define NBUK     293                    // buckets of 512 nodes (293*512=150016)
#define BCAP     8192                   // padded per-bucket capacity (exp 6826, +16 sigma)

__device__ __forceinline__ float wave_sum64(float v) {
    #pragma unroll
    for (int off = 32; off > 0; off >>= 1) v += __shfl_xor(v, off, 64);
    return v;
}

__device__ __forceinline__ float bf2f(unsigned short s) {
    return __uint_as_float(((unsigned int)s) << 16);
}
__device__ __forceinline__ unsigned short f2bf(float f) {   // RNE
    unsigned int u = __float_as_uint(f);
    return (unsigned short)((u + 0x7fffu + ((u >> 16) & 1u)) >> 16);
}

// ---- fused bucket sort: count -> chunk-reserve -> LDS scatter -> coalesced
//      burst write-out. Padded arenas (BCAP/bucket), no global prefix.
//      Within-bucket order arbitrary (re-ranked per node in bfinal).

__global__ __launch_bounds__(512) void sort_kernel(
        const int* __restrict__ row, const int* __restrict__ col,
        const int* __restrict__ ucnt,
        int* __restrict__ gcurC, int* __restrict__ gcurR,
        unsigned int* __restrict__ midC, unsigned short* __restrict__ midR,
        int* __restrict__ n_sel, int* __restrict__ sel_col, float* __restrict__ sel_w) {
    __shared__ unsigned int hr[NBUK], hc[NBUK];
    __shared__ int lofC[NBUK], lofR[NBUK], posC[NBUK], posR[NBUK];
    __shared__ int scan_tmp[512];
    __shared__ unsigned int   stC[EPS];
    __shared__ unsigned short stR[EPS];
    __shared__ unsigned short bmapC[EPS], bmapR[EPS];
    __shared__ int lcnt, lbase;
    __shared__ int2 buf[256];
    int blk = blockIdx.x, t = threadIdx.x;
    for (int i = t; i < NBUK; i += 512) { hr[i] = 0; hc[i] = 0; }
    if (t == 0) lcnt = 0;
    __syncthreads();
    int e0 = blk * EPS;
    int e1 = e0 + EPS; if (e1 > NEDGE) e1 = NEDGE;
    // pass 1: per-bucket counts + batch selection
    for (int base = e0 + t * 4; base < e1; base += 2048) {
        if (base + 4 <= e1) {
            int4 r4 = *(const int4*)(row + base);
            int4 c4 = *(const int4*)(col + base);
            atomicAdd(&hr[r4.x >> 9], 1u);
            atomicAdd(&hr[r4.y >> 9], 1u);
            atomicAdd(&hr[r4.z >> 9], 1u);
            atomicAdd(&hr[r4.w >> 9], 1u);
            atomicAdd(&hc[c4.x >> 9], 1u);
            atomicAdd(&hc[c4.y >> 9], 1u);
            atomicAdd(&hc[c4.z >> 9], 1u);
            atomicAdd(&hc[c4.w >> 9], 1u);
            int u0 = ucnt[r4.x], u1 = ucnt[r4.y], u2 = ucnt[r4.z], u3 = ucnt[r4.w];
            if (u0 > 0) { int i = atomicAdd(&lcnt, 1); if (i < 256) buf[i] = make_int2(c4.x, u0); }
            if (u1 > 0) { int i = atomicAdd(&lcnt, 1); if (i < 256) buf[i] = make_int2(c4.y, u1); }
            if (u2 > 0) { int i = atomicAdd(&lcnt, 1); if (i < 256) buf[i] = make_int2(c4.z, u2); }
            if (u3 > 0) { int i = atomicAdd(&lcnt, 1); if (i < 256) buf[i] = make_int2(c4.w, u3); }
        } else {
            for (int e = base; e < e1; ++e) {
                int r = row[e], c = col[e];
                atomicAdd(&hr[r >> 9], 1u);
                atomicAdd(&hc[c >> 9], 1u);
                int u = ucnt[r];
                if (u > 0) { int i = atomicAdd(&lcnt, 1); if (i < 256) buf[i] = make_int2(c, u); }
            }
        }
    }
    __syncthreads();
    // local exclusive scan over buckets (col)
    scan_tmp[t] = (t < NBUK) ? (int)hc[t] : 0;
    __syncthreads();
    for (int o = 1; o < 512; o <<= 1) {
        int v = (t >= o) ? scan_tmp[t - o] : 0;
        __syncthreads();
        scan_tmp[t] += v;
        __syncthreads();
    }
    if (t < NBUK) lofC[t] = scan_tmp[t] - (int)hc[t];
    __syncthreads();
    // local exclusive scan over buckets (row)
    scan_tmp[t] = (t < NBUK) ? (int)hr[t] : 0;
    __syncthreads();
    for (int o = 1; o < 512; o <<= 1) {
        int v = (t >= o) ? scan_tmp[t - o] : 0;
        __syncthreads();
        scan_tmp[t] += v;
        __syncthreads();
    }
    if (t < NBUK) lofR[t] = scan_tmp[t] - (int)hr[t];
    __syncthreads();
    // chunk reservation (one global atomic per bucket) + bmap + re-zero
    if (t < NBUK) {
        int cc = (int)hc[t], cr = (int)hr[t];
        posC[t] = atomicAdd(&gcurC[t], cc);
        posR[t] = atomicAdd(&gcurR[t], cr);
        int lo = lofC[t];
        for (int k = 0; k < cc; ++k) bmapC[lo + k] = (unsigned short)t;
        lo = lofR[t];
        for (int k = 0; k < cr; ++k) bmapR[lo + k] = (unsigned short)t;
        hc[t] = 0; hr[t] = 0;
    }
    __syncthreads();
    // pass 2: rank via fresh LDS atomics, scatter into LDS (edge re-read L1/L2-hot)
    for (int base = e0 + t * 4; base < e1; base += 2048) {
        if (base + 4 <= e1) {
            int4 r4 = *(const int4*)(row + base);
            int4 c4 = *(const int4*)(col + base);
            int b0 = c4.x >> 9, b1 = c4.y >> 9, b2 = c4.z >> 9, b3 = c4.w >> 9;
            int k0 = lofC[b0] + (int)atomicAdd(&hc[b0], 1u);
            int k1 = lofC[b1] + (int)atomicAdd(&hc[b1], 1u);
            int k2 = lofC[b2] + (int)atomicAdd(&hc[b2], 1u);
            int k3 = lofC[b3] + (int)atomicAdd(&hc[b3], 1u);
            stC[k0] = ((unsigned int)(c4.x & 511) << 18) | (unsigned int)r4.x;
            stC[k1] = ((unsigned int)(c4.y & 511) << 18) | (unsigned int)r4.y;
            stC[k2] = ((unsigned int)(c4.z & 511) << 18) | (unsigned int)r4.z;
            stC[k3] = ((unsigned int)(c4.w & 511) << 18) | (unsigned int)r4.w;
            b0 = r4.x >> 9; b1 = r4.y >> 9; b2 = r4.z >> 9; b3 = r4.w >> 9;
            k0 = lofR[b0] + (int)atomicAdd(&hr[b0], 1u);
            k1 = lofR[b1] + (int)atomicAdd(&hr[b1], 1u);
            k2 = lofR[b2] + (int)atomicAdd(&hr[b2], 1u);
            k3 = lofR[b3] + (int)atomicAdd(&hr[b3], 1u);
            stR[k0] = (unsigned short)(r4.x & 511);
            stR[k1] = (unsigned short)(r4.y & 511);
            stR[k2] = (unsigned short)(r4.z & 511);
            stR[k3] = (unsigned short)(r4.w & 511);
        } else {
            for (int e = base; e < e1; ++e) {
                int r = row[e], c = col[e];
                int bc = c >> 9;
                int kc = lofC[bc] + (int)atomicAdd(&hc[bc], 1u);
                stC[kc] = ((unsigned int)(c & 511) << 18) | (unsigned int)r;
                int br = r >> 9;
                int kr = lofR[br] + (int)atomicAdd(&hr[br], 1u);
                stR[kr] = (unsigned short)(r & 511);
            }
        }
    }
    __syncthreads();
    // coalesced burst write-out: consecutive j in a bucket -> consecutive dst
    int total = e1 - e0;
    for (int j = t; j < total; j += 512) {
        int b = bmapC[j];
        int dst = posC[b] + (j - lofC[b]);
        if (dst < BCAP) midC[(size_t)b * BCAP + dst] = stC[j];
        b = bmapR[j];
        dst = posR[b] + (j - lofR[b]);
        if (dst < BCAP) midR[(size_t)b * BCAP + dst] = stR[j];
    }
    // selection flush
    if (t == 0) {
        int c = lcnt; c = c < 256 ? c : 256;
        lbase = atomicAdd(n_sel, c);
    }
    __syncthreads();
    int c = lcnt; c = c < 256 ? c : 256;
    int b = lbase;
    for (int i = t; i < c; i += 512) {
        int o = b + i;
        if (o < SEL_CAP) { sel_col[o] = buf[i].x; sel_w[o] = (float)buf[i].y; }
    }
}

// ---- stage 2 (fused): col CSR + row deg/dinv + embed->bf16 y0 ------------

__global__ __launch_bounds__(1024) void bfinal_kernel(
        const unsigned int* __restrict__ midC, const int* __restrict__ gcurC,
        const unsigned short* __restrict__ midR, const int* __restrict__ gcurR,
        const float4* __restrict__ embed,
        int* __restrict__ rptr, int* __restrict__ rend, int* __restrict__ src_sorted,
        float* __restrict__ dinv, float* __restrict__ dinv2,
        uint2* __restrict__ y0) {
    __shared__ int cnt[512], sm[512], cur[512];
    __shared__ float dinvL[512];
    int b = blockIdx.x, t = threadIdx.x;
    // --- col part ---
    int s0 = b * BCAP;
    int cc = gcurC[b]; if (cc > BCAP) cc = BCAP;
    int s1 = s0 + cc;
    if (t < 512) cnt[t] = 0;
    __syncthreads();
    for (int i = s0 + t; i < s1; i += 1024) atomicAdd(&cnt[midC[i] >> 18], 1);
    __syncthreads();
    if (t < 512) sm[t] = cnt[t];
    __syncthreads();
    for (int off = 1; off < 512; off <<= 1) {
        int v = 0;
        if (t < 512 && t >= off) v = sm[t - off];
        __syncthreads();
        if (t < 512) sm[t] += v;
        __syncthreads();
    }
    if (t < 512) {
        int excl = s0 + sm[t] - cnt[t];
        int n = b * 512 + t;
        if (n < NNODES) { rptr[n] = excl; rend[n] = s0 + sm[t]; }
        cur[t] = excl;
    }
    if (b == 0 && t < 16) y0[(size_t)NNODES * 16 + t] = make_uint2(0u, 0u); // sentinel zero row
    __syncthreads();
    for (int i = s0 + t; i < s1; i += 1024) {
        unsigned int v = midC[i];
        int dst = atomicAdd(&cur[v >> 18], 1);
        src_sorted[dst] = (int)(v & 0x3FFFFu);
    }
    __syncthreads();
    // --- row part (deg) ---
    if (t < 512) cnt[t] = 0;
    __syncthreads();
    int r0 = b * BCAP;
    int rc = gcurR[b]; if (rc > BCAP) rc = BCAP;
    int r1 = r0 + rc;
    for (int i = r0 + t; i < r1; i += 1024) atomicAdd(&cnt[midR[i]], 1);
    __syncthreads();
    if (t < 512) {
        int n = b * 512 + t;
        if (n < NNODES) {
            float d = fmaxf((float)cnt[t], 1.0f);
            float di = rsqrtf(d);
            dinv[n] = di; dinv2[n] = 1.0f / d;
            dinvL[t] = di;
        }
    }
    __syncthreads();
    // --- cvt part: y0 = bf16(dinv * embed) for this node range ---
    int nbase = b * 512;
    int nmax = NNODES - nbase; if (nmax > 512) nmax = 512;
    if (nmax < 0) nmax = 0;
    for (int i = t; i < nmax * 16; i += 1024) {
        int ln = i >> 4, slot = i & 15;
        float d = dinvL[ln];
        float4 v = embed[(size_t)(nbase + ln) * 16 + slot];
        unsigned int w0 = (unsigned int)f2bf(v.x * d) | ((unsigned int)f2bf(v.y * d) << 16);
        unsigned int w1 = (unsigned int)f2bf(v.z * d) | ((unsigned int)f2bf(v.w * d) << 16);
        y0[(size_t)(nbase + ln) * 16 + slot] = make_uint2(w0, w1);
    }
}

// ---- propagation: 8 lanes/node, uint4 (8 bf16)/lane; src-prefetch pipeline,
//      parallel sentinel tail (node NNODES is an always-zero row) -----------

#define ACC8(V) do { \
    a0 += __uint_as_float((V).x << 16); a1 += __uint_as_float((V).x & 0xffff0000u); \
    a2 += __uint_as_float((V).y << 16); a3 += __uint_as_float((V).y & 0xffff0000u); \
    a4 += __uint_as_float((V).z << 16); a5 += __uint_as_float((V).z & 0xffff0000u); \
    a6 += __uint_as_float((V).w << 16); a7 += __uint_as_float((V).w & 0xffff0000u); \
} while (0)

// shared gather body: accumulate neighbors of `node`, write x_out row
__device__ __forceinline__ void prop_node(
        const uint4* __restrict__ x_in, uint4* __restrict__ x_out,
        const int* __restrict__ ptr, const int* __restrict__ rend,
        const int* __restrict__ src,
        const float* __restrict__ scale, int node, int sl) {
    int i = ptr[node], e = rend[node];
    float sc = scale[node];
    float a0 = 0.f, a1 = 0.f, a2 = 0.f, a3 = 0.f;
    float a4 = 0.f, a5 = 0.f, a6 = 0.f, a7 = 0.f;
    int p0, p1, p2, p3;
    if (i + 4 <= e) { p0 = src[i]; p1 = src[i + 1]; p2 = src[i + 2]; p3 = src[i + 3]; }
    while (i + 8 <= e) {
        uint4 w0 = x_in[p0 * 8 + sl];
        uint4 w1 = x_in[p1 * 8 + sl];
        uint4 w2 = x_in[p2 * 8 + sl];
        uint4 w3 = x_in[p3 * 8 + sl];
        p0 = src[i + 4]; p1 = src[i + 5]; p2 = src[i + 6]; p3 = src[i + 7];
        i += 4;
        ACC8(w0); ACC8(w1); ACC8(w2); ACC8(w3);
    }
    if (i + 4 <= e) {
        uint4 w0 = x_in[p0 * 8 + sl];
        uint4 w1 = x_in[p1 * 8 + sl];
        uint4 w2 = x_in[p2 * 8 + sl];
        uint4 w3 = x_in[p3 * 8 + sl];
        i += 4;
        ACC8(w0); ACC8(w1); ACC8(w2); ACC8(w3);
    }
    if (i < e) {               // tail 1..3: clamp to sentinel zero row
        int q0 = src[i];
        int q1 = (i + 1 < e) ? src[i + 1] : NNODES;
        int q2 = (i + 2 < e) ? src[i + 2] : NNODES;
        uint4 w0 = x_in[q0 * 8 + sl];
        uint4 w1 = x_in[q1 * 8 + sl];
        uint4 w2 = x_in[q2 * 8 + sl];
        ACC8(w0); ACC8(w1); ACC8(w2);
    }
    uint4 o;
    o.x = (unsigned int)f2bf(a0 * sc) | ((unsigned int)f2bf(a1 * sc) << 16);
    o.y = (unsigned int)f2bf(a2 * sc) | ((unsigned int)f2bf(a3 * sc) << 16);
    o.z = (unsigned int)f2bf(a4 * sc) | ((unsigned int)f2bf(a5 * sc) << 16);
    o.w = (unsigned int)f2bf(a6 * sc) | ((unsigned int)f2bf(a7 * sc) << 16);
    x_out[(size_t)node * 8 + sl] = o;
}

__global__ __launch_bounds__(256, 8) void prop_kernel(
        const uint4* __restrict__ x_in, uint4* __restrict__ x_out,
        const int* __restrict__ ptr, const int* __restrict__ rend,
        const int* __restrict__ src,
        const float* __restrict__ scale) {
    int gid  = blockIdx.x * blockDim.x + threadIdx.x;
    int node = gid >> 3;       // 8 lanes per node
    int sl   = gid & 7;        // lane's 8-dim slot within the row
    if (node > NNODES) return;
    if (node == NNODES) {      // keep sentinel row zero for next layer
        x_out[(size_t)node * 8 + sl] = make_uint4(0u, 0u, 0u, 0u);
        return;
    }
    prop_node(x_in, x_out, ptr, rend, src, scale, node, sl);
}

// layer 3: only nodes consumed downstream — users, items+NUM_USERS, sel_col.
__global__ __launch_bounds__(256, 8) void prop_list_kernel(
        const uint4* __restrict__ x_in, uint4* __restrict__ x_out,
        const int* __restrict__ ptr, const int* __restrict__ rend,
        const int* __restrict__ src,
        const float* __restrict__ scale,
        const int* __restrict__ users, const int* __restrict__ items,
        const int* __restrict__ sel_col, const int* __restrict__ n_sel_p) {
    int n = *n_sel_p; if (n > SEL_CAP) n = SEL_CAP;
    int total = (2 * BATCH + n) * 8;
    int nth = gridDim.x * blockDim.x;
    for (int gid = blockIdx.x * blockDim.x + threadIdx.x; gid < total; gid += nth) {
        int li = gid >> 3;
        int sl = gid & 7;
        int node;
        if (li < BATCH) {
            node = users[li];
        } else if (li < 2 * BATCH) {
            node = items[li - BATCH] + NUM_USERS;
        } else {
            node = sel_col[li - 2 * BATCH];
        }
        prop_node(x_in, x_out, ptr, rend, src, scale, node, sl);
    }
}

// ---- batch / softmax part (x is bf16) -----------------------------------

__global__ void ucnt_kernel(const int* __restrict__ users, int* __restrict__ ucnt) {
    int b = blockIdx.x * blockDim.x + threadIdx.x;
    if (b < BATCH) atomicAdd(&ucnt[users[b]], 1);
}

// 64 blocks x 16 users; one atomicAdd per lane into zeroed ctx (raw sum).
__global__ __launch_bounds__(256) void ctx_part_kernel(
        const unsigned short* __restrict__ x, const int* __restrict__ users,
        float* __restrict__ ctx) {
    __shared__ float sm[256];
    int lane = threadIdx.x & 63, wl = threadIdx.x >> 6;
    int b0 = blockIdx.x * 16 + wl * 4;
    float acc = 0.0f;
    #pragma unroll
    for (int k = 0; k < 4; ++k)
        acc += bf2f(x[users[b0 + k] * DIM + lane]);
    sm[threadIdx.x] = acc;
    __syncthreads();
    if (wl == 0)
        atomicAdd(&ctx[lane], sm[lane] + sm[64 + lane] + sm[128 + lane] + sm[192 + lane]);
}

__global__ void softmax_kernel(const unsigned short* __restrict__ x,
                               const float* __restrict__ ctx,
                               const int* __restrict__ sel_col,
                               const float* __restrict__ sel_w,
                               const int* __restrict__ n_sel_p,
                               float* __restrict__ S, float* __restrict__ zp) {
    __shared__ float smS[4 * 64];
    __shared__ float smZ[4];
    int lane = threadIdx.x & 63, wl = threadIdx.x >> 6;
    int n = *n_sel_p; if (n > SEL_CAP) n = SEL_CAP;
    float c = ctx[lane] * (1.0f / BATCH);   // ctx holds raw sum over users
    float accS = 0.0f, accZ = 0.0f;
    int stride = gridDim.x * 4;
    for (int idx = blockIdx.x * 4 + wl; idx < n; idx += stride) {
        int node = sel_col[idx];
        float xv = bf2f(x[node * DIM + lane]);
        float v = wave_sum64(xv * c);
        float w = sel_w[idx] * __expf(v);
        accS = fmaf(w, xv, accS);
        accZ += w;
    }
    smS[wl * 64 + lane] = accS;
    if (lane == 0) smZ[wl] = accZ;
    __syncthreads();
    if (wl == 0) {
        float s = smS[lane] + smS[64 + lane] + smS[128 + lane] + smS[192 + lane];
        atomicAdd(&S[lane], s);
    }
    if (threadIdx.x == 0) atomicAdd(zp, smZ[0] + smZ[1] + smZ[2] + smZ[3]);
}

__global__ void score_kernel(const unsigned short* __restrict__ x, const int* __restrict__ users,
                             const int* __restrict__ items, const float* __restrict__ S,
                             const float* __restrict__ zp, float* __restrict__ out) {
    int gid = blockIdx.x * blockDim.x + threadIdx.x;
    int b = gid >> 6, lane = gid & 63;
    if (b >= BATCH) return;
    float z = fmaxf(*zp, 1e-12f);
    float na = S[lane] / z;
    int u = users[b], it = items[b] + NUM_USERS;
    float v = bf2f(x[u * DIM + lane]) * (bf2f(x[it * DIM + lane]) + na);
    v = wave_sum64(v);
    if (lane == 0) out[b] = 1.0f / (1.0f + __expf(-v));
}

// ---- launch -------------------------------------------------------------

extern "C" void kernel_launch(void* const* d_in, const int* in_sizes, int n_in,
                              void* d_out, int out_size, void* d_ws, size_t ws_size,
                              hipStream_t stream) {
    const float* embed = (const float*)d_in[0];
    const int*   edge  = (const int*)d_in[1];
    const int*   row   = edge;
    const int*   col   = edge + NEDGE;
    const int*   users = (const int*)d_in[2];
    const int*   items = (const int*)d_in[3];
    float*       out   = (float*)d_out;
    char*        ws    = (char*)d_ws;

    size_t off = 0;
    auto A = [&](size_t bytes) { size_t o = off; off += (bytes + 255) & ~(size_t)255; return o; };
    size_t o_midC  = A((size_t)NBUK * BCAP * 4);            // 9.6 MB padded
    size_t o_midR  = A((size_t)NBUK * BCAP * 2);            // 4.8 MB padded
    size_t o_xa    = A((size_t)(NNODES + 1) * DIM * 2);     // +1: sentinel zero row
    size_t o_xb    = A((size_t)(NNODES + 1) * DIM * 2);
    size_t o_src   = A((size_t)NBUK * BCAP * 4);            // 9.6 MB padded, alive thru prop
    size_t o_selc  = A((size_t)SEL_CAP * 4);
    size_t o_selw  = A((size_t)SEL_CAP * 4);
    size_t o_zero  = off;                                   // ---- zeroed block ----
    size_t o_ucnt  = A((size_t)NNODES * 4);
    size_t o_gcurC = A((size_t)NBUK * 4);
    size_t o_gcurR = A((size_t)NBUK * 4);
    size_t o_misc  = A(1024);                               // n_sel@0, z@8, S@256, ctx@512
    size_t zero_bytes = off - o_zero;                       // ---- end zero -------
    size_t o_dinv  = A((size_t)NNODES * 4);
    size_t o_dinv2 = A((size_t)NNODES * 4);
    size_t o_rptr  = A((size_t)NNODES * 4);
    size_t o_rend  = A((size_t)NNODES * 4);

    unsigned int*   midC = (unsigned int*)(ws + o_midC);
    unsigned short* midR = (unsigned short*)(ws + o_midR);
    unsigned short* xa   = (unsigned short*)(ws + o_xa);
    unsigned short* xb   = (unsigned short*)(ws + o_xb);
    int*   srcS  = (int*)(ws + o_src);
    int*   selc  = (int*)(ws + o_selc);
    float* selw  = (float*)(ws + o_selw);
    int*   ucnt  = (int*)(ws + o_ucnt);
    int*   gcurC = (int*)(ws + o_gcurC);
    int*   gcurR = (int*)(ws + o_gcurR);
    int*   nsel  = (int*)(ws + o_misc);
    float* zp    = (float*)(ws + o_misc + 8);
    float* S     = (float*)(ws + o_misc + 256);
    float* ctx   = (float*)(ws + o_misc + 512);
    float* dinv  = (float*)(ws + o_dinv);
    float* dinv2 = (float*)(ws + o_dinv2);
    int*   rptr  = (int*)(ws + o_rptr);
    int*   rend  = (int*)(ws + o_rend);

    hipMemsetAsync(ws + o_zero, 0, zero_bytes, stream);

    ucnt_kernel<<<(BATCH + 255) / 256, 256, 0, stream>>>(users, ucnt);

    // fused bucket sort (count + reserve + LDS scatter + coalesced write + selection)
    sort_kernel<<<SLICES, 512, 0, stream>>>(row, col, ucnt, gcurC, gcurR,
                                            midC, midR, nsel, selc, selw);
    // fused: col CSR + row deg + embed->y0 conversion
    bfinal_kernel<<<NBUK, 1024, 0, stream>>>(midC, gcurC, midR, gcurR,
                                             (const float4*)embed, rptr, rend, srcS,
                                             dinv, dinv2, (uint2*)xa);

    // layers 1,2 full: y->y (dinv2), y->y (dinv2); layer 3 selective: y->x (dinv)
    int prop_blocks = ((NNODES + 1) * 8 + 255) / 256;
    prop_kernel<<<prop_blocks, 256, 0, stream>>>((const uint4*)xa, (uint4*)xb, rptr, rend, srcS, dinv2);
    prop_kernel<<<prop_blocks, 256, 0, stream>>>((const uint4*)xb, (uint4*)xa, rptr, rend, srcS, dinv2);
    prop_list_kernel<<<1024, 256, 0, stream>>>((const uint4*)xa, (uint4*)xb,
                                               rptr, rend, srcS, dinv,
                                               users, items, selc, nsel);
    // final x rows (users/items/sel) live in xb

    // batch softmax aggregation over selected edges (mx = 0, fused)
    ctx_part_kernel<<<64, 256, 0, stream>>>(xb, users, ctx);
    softmax_kernel<<<LOGIT_BLOCKS, 256, 0, stream>>>(xb, ctx, selc, selw, nsel, S, zp);

    // final scores
    score_kernel<<<(BATCH * 64 + 255) / 256, 256, 0, stream>>>(xb, users, items, S, zp, out);
}

// Round 9
// 256.383 us; speedup vs baseline: 1.0912x; 1.0070x over previous
//
#include <hip/hip_runtime.h>
#include <float.h>
#include <math.h>

#define NUM_USERS 100000
#define NUM_ITEMS 50000
#define NNODES    150000
#define DIM       64
#define NEDGE     2000000
#define BATCH     1024
#define SEL_CAP   (1 << 18)
#define LOGIT_BLOCKS 512

#define SLICES   1024                   // edge slices (all blocks resident: 4/CU)
#define EPS      1956                   // ceil(NEDGE/SLICES) rounded to x4
#define NBUK     293                    // buckets of 512 nodes (293*512=150016)
#define BCAP     8192                   // padded per-bucket capacity (exp 6826, +16 sigma)
#define SCAP     16                     // fixed LDS slots per bucket (exp 6.7/slice)

__device__ __forceinline__ float wave_sum64(float v) {
    #pragma unroll
    for (int off = 32; off > 0; off >>= 1) v += __shfl_xor(v, off, 64);
    return v;
}

__device__ __forceinline__ float bf2f(unsigned short s) {
    return __uint_as_float(((unsigned int)s) << 16);
}
__device__ __forceinline__ unsigned short f2bf(float f) {   // RNE
    unsigned int u = __float_as_uint(f);
    return (unsigned short)((u + 0x7fffu + ((u >> 16) & 1u)) >> 16);
}

// ---- fused bucket sort, single pass, fixed-capacity LDS slots ------------
// Each bucket gets SCAP fixed LDS slots (no scan/bmap/second pass; 3 barriers).
// Rare overflow (Poisson tail) spills to a small buffer, drained via global
// atomics — bit-exact correct, negligible cost. Within-bucket order is
// arbitrary (re-ranked per node in bfinal).

__global__ __launch_bounds__(512) void sort_kernel(
        const int* __restrict__ row, const int* __restrict__ col,
        const int* __restrict__ ucnt,
        int* __restrict__ gcurC, int* __restrict__ gcurR,
        unsigned int* __restrict__ midC, unsigned short* __restrict__ midR,
        int* __restrict__ n_sel, int* __restrict__ sel_col, float* __restrict__ sel_w) {
    __shared__ unsigned int hc[NBUK], hr[NBUK];
    __shared__ int posC[NBUK], posR[NBUK];
    __shared__ unsigned int   stC[NBUK * SCAP];
    __shared__ unsigned short stR[NBUK * SCAP];
    __shared__ int lcnt, lbase, novfC, novfR;
    __shared__ uint2 ovfC[64];          // (bucket, packed value)
    __shared__ unsigned int ovfR[64];   // bucket<<9 | (r&511)
    __shared__ int2 buf[256];
    int blk = blockIdx.x, t = threadIdx.x;
    for (int i = t; i < NBUK; i += 512) { hc[i] = 0; hr[i] = 0; }
    if (t == 0) { lcnt = 0; novfC = 0; novfR = 0; }
    __syncthreads();
    int e0 = blk * EPS;
    int e1 = e0 + EPS; if (e1 > NEDGE) e1 = NEDGE;
    // single edge pass: rank via LDS atomic -> fixed slot; selection fused
    for (int base = e0 + t * 4; base < e1; base += 2048) {
        if (base + 4 <= e1) {
            int4 r4 = *(const int4*)(row + base);
            int4 c4 = *(const int4*)(col + base);
            #pragma unroll
            for (int q = 0; q < 4; ++q) {
                int c = (q == 0) ? c4.x : (q == 1) ? c4.y : (q == 2) ? c4.z : c4.w;
                int r = (q == 0) ? r4.x : (q == 1) ? r4.y : (q == 2) ? r4.z : r4.w;
                int bc = c >> 9;
                unsigned int kc = atomicAdd(&hc[bc], 1u);
                unsigned int v = ((unsigned int)(c & 511) << 18) | (unsigned int)r;
                if (kc < SCAP) stC[bc * SCAP + kc] = v;
                else { int i = atomicAdd(&novfC, 1); if (i < 64) ovfC[i] = make_uint2((unsigned int)bc, v); }
                int br = r >> 9;
                unsigned int kr = atomicAdd(&hr[br], 1u);
                if (kr < SCAP) stR[br * SCAP + kr] = (unsigned short)(r & 511);
                else { int i = atomicAdd(&novfR, 1); if (i < 64) ovfR[i] = ((unsigned int)br << 9) | (unsigned int)(r & 511); }
                int u = ucnt[r];
                if (u > 0) { int i = atomicAdd(&lcnt, 1); if (i < 256) buf[i] = make_int2(c, u); }
            }
        } else {
            for (int e = base; e < e1; ++e) {
                int r = row[e], c = col[e];
                int bc = c >> 9;
                unsigned int kc = atomicAdd(&hc[bc], 1u);
                unsigned int v = ((unsigned int)(c & 511) << 18) | (unsigned int)r;
                if (kc < SCAP) stC[bc * SCAP + kc] = v;
                else { int i = atomicAdd(&novfC, 1); if (i < 64) ovfC[i] = make_uint2((unsigned int)bc, v); }
                int br = r >> 9;
                unsigned int kr = atomicAdd(&hr[br], 1u);
                if (kr < SCAP) stR[br * SCAP + kr] = (unsigned short)(r & 511);
                else { int i = atomicAdd(&novfR, 1); if (i < 64) ovfR[i] = ((unsigned int)br << 9) | (unsigned int)(r & 511); }
                int u = ucnt[r];
                if (u > 0) { int i = atomicAdd(&lcnt, 1); if (i < 256) buf[i] = make_int2(c, u); }
            }
        }
    }
    __syncthreads();
    // chunk reservation: one global atomic per bucket (capped counts)
    if (t < NBUK) {
        int cc = (int)hc[t]; if (cc > SCAP) cc = SCAP;
        int cr = (int)hr[t]; if (cr > SCAP) cr = SCAP;
        posC[t] = atomicAdd(&gcurC[t], cc);
        posR[t] = atomicAdd(&gcurR[t], cr);
    }
    if (t == 0) {
        int c = lcnt; c = c < 256 ? c : 256;
        lbase = atomicAdd(n_sel, c);
    }
    __syncthreads();
    // write-out: strided over fixed slots; chunk-contiguous global dst
    for (int j = t; j < NBUK * SCAP; j += 512) {
        int b = j >> 4, k = j & (SCAP - 1);
        int cc = (int)hc[b]; if (cc > SCAP) cc = SCAP;
        if (k < cc) {
            int d = posC[b] + k;
            if (d < BCAP) midC[(size_t)b * BCAP + d] = stC[j];
        }
        int cr = (int)hr[b]; if (cr > SCAP) cr = SCAP;
        if (k < cr) {
            int d = posR[b] + k;
            if (d < BCAP) midR[(size_t)b * BCAP + d] = stR[j];
        }
    }
    // overflow drain (expected ~0-20 edges per RUN, not per block)
    int nc = novfC; nc = nc < 64 ? nc : 64;
    for (int i = t; i < nc; i += 512) {
        int b = (int)ovfC[i].x;
        int d = atomicAdd(&gcurC[b], 1);
        if (d < BCAP) midC[(size_t)b * BCAP + d] = ovfC[i].y;
    }
    int nr = novfR; nr = nr < 64 ? nr : 64;
    for (int i = t; i < nr; i += 512) {
        unsigned int pv = ovfR[i];
        int b = (int)(pv >> 9);
        int d = atomicAdd(&gcurR[b], 1);
        if (d < BCAP) midR[(size_t)b * BCAP + d] = (unsigned short)(pv & 511u);
    }
    // selection flush
    int c = lcnt; c = c < 256 ? c : 256;
    int b = lbase;
    for (int i = t; i < c; i += 512) {
        int o = b + i;
        if (o < SEL_CAP) { sel_col[o] = buf[i].x; sel_w[o] = (float)buf[i].y; }
    }
}

// ---- stage 2 (fused): col CSR + row deg/dinv + embed->bf16 y0 ------------

__global__ __launch_bounds__(1024) void bfinal_kernel(
        const unsigned int* __restrict__ midC, const int* __restrict__ gcurC,
        const unsigned short* __restrict__ midR, const int* __restrict__ gcurR,
        const float4* __restrict__ embed,
        int* __restrict__ rptr, int* __restrict__ rend, int* __restrict__ src_sorted,
        float* __restrict__ dinv, float* __restrict__ dinv2,
        uint2* __restrict__ y0) {
    __shared__ int cnt[512], sm[512], cur[512];
    __shared__ float dinvL[512];
    int b = blockIdx.x, t = threadIdx.x;
    // --- col part ---
    int s0 = b * BCAP;
    int cc = gcurC[b]; if (cc > BCAP) cc = BCAP;
    int s1 = s0 + cc;
    if (t < 512) cnt[t] = 0;
    __syncthreads();
    for (int i = s0 + t; i < s1; i += 1024) atomicAdd(&cnt[midC[i] >> 18], 1);
    __syncthreads();
    if (t < 512) sm[t] = cnt[t];
    __syncthreads();
    for (int off = 1; off < 512; off <<= 1) {
        int v = 0;
        if (t < 512 && t >= off) v = sm[t - off];
        __syncthreads();
        if (t < 512) sm[t] += v;
        __syncthreads();
    }
    if (t < 512) {
        int excl = s0 + sm[t] - cnt[t];
        int n = b * 512 + t;
        if (n < NNODES) { rptr[n] = excl; rend[n] = s0 + sm[t]; }
        cur[t] = excl;
    }
    if (b == 0 && t < 16) y0[(size_t)NNODES * 16 + t] = make_uint2(0u, 0u); // sentinel zero row
    __syncthreads();
    for (int i = s0 + t; i < s1; i += 1024) {
        unsigned int v = midC[i];
        int dst = atomicAdd(&cur[v >> 18], 1);
        src_sorted[dst] = (int)(v & 0x3FFFFu);
    }
    __syncthreads();
    // --- row part (deg) ---
    if (t < 512) cnt[t] = 0;
    __syncthreads();
    int r0 = b * BCAP;
    int rc = gcurR[b]; if (rc > BCAP) rc = BCAP;
    int r1 = r0 + rc;
    for (int i = r0 + t; i < r1; i += 1024) atomicAdd(&cnt[midR[i]], 1);
    __syncthreads();
    if (t < 512) {
        int n = b * 512 + t;
        if (n < NNODES) {
            float d = fmaxf((float)cnt[t], 1.0f);
            float di = rsqrtf(d);
            dinv[n] = di; dinv2[n] = 1.0f / d;
            dinvL[t] = di;
        }
    }
    __syncthreads();
    // --- cvt part: y0 = bf16(dinv * embed) for this node range ---
    int nbase = b * 512;
    int nmax = NNODES - nbase; if (nmax > 512) nmax = 512;
    if (nmax < 0) nmax = 0;
    for (int i = t; i < nmax * 16; i += 1024) {
        int ln = i >> 4, slot = i & 15;
        float d = dinvL[ln];
        float4 v = embed[(size_t)(nbase + ln) * 16 + slot];
        unsigned int w0 = (unsigned int)f2bf(v.x * d) | ((unsigned int)f2bf(v.y * d) << 16);
        unsigned int w1 = (unsigned int)f2bf(v.z * d) | ((unsigned int)f2bf(v.w * d) << 16);
        y0[(size_t)(nbase + ln) * 16 + slot] = make_uint2(w0, w1);
    }
}

// ---- propagation: 8 lanes/node, uint4 (8 bf16)/lane; src-prefetch pipeline,
//      parallel sentinel tail (node NNODES is an always-zero row) -----------

#define ACC8(V) do { \
    a0 += __uint_as_float((V).x << 16); a1 += __uint_as_float((V).x & 0xffff0000u); \
    a2 += __uint_as_float((V).y << 16); a3 += __uint_as_float((V).y & 0xffff0000u); \
    a4 += __uint_as_float((V).z << 16); a5 += __uint_as_float((V).z & 0xffff0000u); \
    a6 += __uint_as_float((V).w << 16); a7 += __uint_as_float((V).w & 0xffff0000u); \
} while (0)

// shared gather body: accumulate neighbors of `node`, write x_out row
__device__ __forceinline__ void prop_node(
        const uint4* __restrict__ x_in, uint4* __restrict__ x_out,
        const int* __restrict__ ptr, const int* __restrict__ rend,
        const int* __restrict__ src,
        const float* __restrict__ scale, int node, int sl) {
    int i = ptr[node], e = rend[node];
    float sc = scale[node];
    float a0 = 0.f, a1 = 0.f, a2 = 0.f, a3 = 0.f;
    float a4 = 0.f, a5 = 0.f, a6 = 0.f, a7 = 0.f;
    int p0, p1, p2, p3;
    if (i + 4 <= e) { p0 = src[i]; p1 = src[i + 1]; p2 = src[i + 2]; p3 = src[i + 3]; }
    while (i + 8 <= e) {
        uint4 w0 = x_in[p0 * 8 + sl];
        uint4 w1 = x_in[p1 * 8 + sl];
        uint4 w2 = x_in[p2 * 8 + sl];
        uint4 w3 = x_in[p3 * 8 + sl];
        p0 = src[i + 4]; p1 = src[i + 5]; p2 = src[i + 6]; p3 = src[i + 7];
        i += 4;
        ACC8(w0); ACC8(w1); ACC8(w2); ACC8(w3);
    }
    if (i + 4 <= e) {
        uint4 w0 = x_in[p0 * 8 + sl];
        uint4 w1 = x_in[p1 * 8 + sl];
        uint4 w2 = x_in[p2 * 8 + sl];
        uint4 w3 = x_in[p3 * 8 + sl];
        i += 4;
        ACC8(w0); ACC8(w1); ACC8(w2); ACC8(w3);
    }
    if (i < e) {               // tail 1..3: clamp to sentinel zero row
        int q0 = src[i];
        int q1 = (i + 1 < e) ? src[i + 1] : NNODES;
        int q2 = (i + 2 < e) ? src[i + 2] : NNODES;
        uint4 w0 = x_in[q0 * 8 + sl];
        uint4 w1 = x_in[q1 * 8 + sl];
        uint4 w2 = x_in[q2 * 8 + sl];
        ACC8(w0); ACC8(w1); ACC8(w2);
    }
    uint4 o;
    o.x = (unsigned int)f2bf(a0 * sc) | ((unsigned int)f2bf(a1 * sc) << 16);
    o.y = (unsigned int)f2bf(a2 * sc) | ((unsigned int)f2bf(a3 * sc) << 16);
    o.z = (unsigned int)f2bf(a4 * sc) | ((unsigned int)f2bf(a5 * sc) << 16);
    o.w = (unsigned int)f2bf(a6 * sc) | ((unsigned int)f2bf(a7 * sc) << 16);
    x_out[(size_t)node * 8 + sl] = o;
}

__global__ __launch_bounds__(256, 8) void prop_kernel(
        const uint4* __restrict__ x_in, uint4* __restrict__ x_out,
        const int* __restrict__ ptr, const int* __restrict__ rend,
        const int* __restrict__ src,
        const float* __restrict__ scale) {
    int gid  = blockIdx.x * blockDim.x + threadIdx.x;
    int node = gid >> 3;       // 8 lanes per node
    int sl   = gid & 7;        // lane's 8-dim slot within the row
    if (node > NNODES) return;
    if (node == NNODES) {      // keep sentinel row zero for next layer
        x_out[(size_t)node * 8 + sl] = make_uint4(0u, 0u, 0u, 0u);
        return;
    }
    prop_node(x_in, x_out, ptr, rend, src, scale, node, sl);
}

// layer 3: only nodes consumed downstream — users, items+NUM_USERS, sel_col.
__global__ __launch_bounds__(256, 8) void prop_list_kernel(
        const uint4* __restrict__ x_in, uint4* __restrict__ x_out,
        const int* __restrict__ ptr, const int* __restrict__ rend,
        const int* __restrict__ src,
        const float* __restrict__ scale,
        const int* __restrict__ users, const int* __restrict__ items,
        const int* __restrict__ sel_col, const int* __restrict__ n_sel_p) {
    int n = *n_sel_p; if (n > SEL_CAP) n = SEL_CAP;
    int total = (2 * BATCH + n) * 8;
    int nth = gridDim.x * blockDim.x;
    for (int gid = blockIdx.x * blockDim.x + threadIdx.x; gid < total; gid += nth) {
        int li = gid >> 3;
        int sl = gid & 7;
        int node;
        if (li < BATCH) {
            node = users[li];
        } else if (li < 2 * BATCH) {
            node = items[li - BATCH] + NUM_USERS;
        } else {
            node = sel_col[li - 2 * BATCH];
        }
        prop_node(x_in, x_out, ptr, rend, src, scale, node, sl);
    }
}

// ---- batch / softmax part (x is bf16) -----------------------------------

__global__ void ucnt_kernel(const int* __restrict__ users, int* __restrict__ ucnt) {
    int b = blockIdx.x * blockDim.x + threadIdx.x;
    if (b < BATCH) atomicAdd(&ucnt[users[b]], 1);
}

// 64 blocks x 16 users; one atomicAdd per lane into zeroed ctx (raw sum).
__global__ __launch_bounds__(256) void ctx_part_kernel(
        const unsigned short* __restrict__ x, const int* __restrict__ users,
        float* __restrict__ ctx) {
    __shared__ float sm[256];
    int lane = threadIdx.x & 63, wl = threadIdx.x >> 6;
    int b0 = blockIdx.x * 16 + wl * 4;
    float acc = 0.0f;
    #pragma unroll
    for (int k = 0; k < 4; ++k)
        acc += bf2f(x[users[b0 + k] * DIM + lane]);
    sm[threadIdx.x] = acc;
    __syncthreads();
    if (wl == 0)
        atomicAdd(&ctx[lane], sm[lane] + sm[64 + lane] + sm[128 + lane] + sm[192 + lane]);
}

__global__ void softmax_kernel(const unsigned short* __restrict__ x,
                               const float* __restrict__ ctx,
                               const int* __restrict__ sel_col,
                               const float* __restrict__ sel_w,
                               const int* __restrict__ n_sel_p,
                               float* __restrict__ S, float* __restrict__ zp) {
    __shared__ float smS[4 * 64];
    __shared__ float smZ[4];
    int lane = threadIdx.x & 63, wl = threadIdx.x >> 6;
    int n = *n_sel_p; if (n > SEL_CAP) n = SEL_CAP;
    float c = ctx[lane] * (1.0f / BATCH);   // ctx holds raw sum over users
    float accS = 0.0f, accZ = 0.0f;
    int stride = gridDim.x * 4;
    for (int idx = blockIdx.x * 4 + wl; idx < n; idx += stride) {
        int node = sel_col[idx];
        float xv = bf2f(x[node * DIM + lane]);
        float v = wave_sum64(xv * c);
        float w = sel_w[idx] * __expf(v);
        accS = fmaf(w, xv, accS);
        accZ += w;
    }
    smS[wl * 64 + lane] = accS;
    if (lane == 0) smZ[wl] = accZ;
    __syncthreads();
    if (wl == 0) {
        float s = smS[lane] + smS[64 + lane] + smS[128 + lane] + smS[192 + lane];
        atomicAdd(&S[lane], s);
    }
    if (threadIdx.x == 0) atomicAdd(zp, smZ[0] + smZ[1] + smZ[2] + smZ[3]);
}

__global__ void score_kernel(const unsigned short* __restrict__ x, const int* __restrict__ users,
                             const int* __restrict__ items, const float* __restrict__ S,
                             const float* __restrict__ zp, float* __restrict__ out) {
    int gid = blockIdx.x * blockDim.x + threadIdx.x;
    int b = gid >> 6, lane = gid & 63;
    if (b >= BATCH) return;
    float z = fmaxf(*zp, 1e-12f);
    float na = S[lane] / z;
    int u = users[b], it = items[b] + NUM_USERS;
    float v = bf2f(x[u * DIM + lane]) * (bf2f(x[it * DIM + lane]) + na);
    v = wave_sum64(v);
    if (lane == 0) out[b] = 1.0f / (1.0f + __expf(-v));
}

// ---- launch -------------------------------------------------------------

extern "C" void kernel_launch(void* const* d_in, const int* in_sizes, int n_in,
                              void* d_out, int out_size, void* d_ws, size_t ws_size,
                              hipStream_t stream) {
    const float* embed = (const float*)d_in[0];
    const int*   edge  = (const int*)d_in[1];
    const int*   row   = edge;
    const int*   col   = edge + NEDGE;
    const int*   users = (const int*)d_in[2];
    const int*   items = (const int*)d_in[3];
    float*       out   = (float*)d_out;
    char*        ws    = (char*)d_ws;

    size_t off = 0;
    auto A = [&](size_t bytes) { size_t o = off; off += (bytes + 255) & ~(size_t)255; return o; };
    size_t o_midC  = A((size_t)NBUK * BCAP * 4);            // 9.6 MB padded
    size_t o_midR  = A((size_t)NBUK * BCAP * 2);            // 4.8 MB padded
    size_t o_xa    = A((size_t)(NNODES + 1) * DIM * 2);     // +1: sentinel zero row
    size_t o_xb    = A((size_t)(NNODES + 1) * DIM * 2);
    size_t o_src   = A((size_t)NBUK * BCAP * 4);            // 9.6 MB padded, alive thru prop
    size_t o_selc  = A((size_t)SEL_CAP * 4);
    size_t o_selw  = A((size_t)SEL_CAP * 4);
    size_t o_zero  = off;                                   // ---- zeroed block ----
    size_t o_ucnt  = A((size_t)NNODES * 4);
    size_t o_gcurC = A((size_t)NBUK * 4);
    size_t o_gcurR = A((size_t)NBUK * 4);
    size_t o_misc  = A(1024);                               // n_sel@0, z@8, S@256, ctx@512
    size_t zero_bytes = off - o_zero;                       // ---- end zero -------
    size_t o_dinv  = A((size_t)NNODES * 4);
    size_t o_dinv2 = A((size_t)NNODES * 4);
    size_t o_rptr  = A((size_t)NNODES * 4);
    size_t o_rend  = A((size_t)NNODES * 4);

    unsigned int*   midC = (unsigned int*)(ws + o_midC);
    unsigned short* midR = (unsigned short*)(ws + o_midR);
    unsigned short* xa   = (unsigned short*)(ws + o_xa);
    unsigned short* xb   = (unsigned short*)(ws + o_xb);
    int*   srcS  = (int*)(ws + o_src);
    int*   selc  = (int*)(ws + o_selc);
    float* selw  = (float*)(ws + o_selw);
    int*   ucnt  = (int*)(ws + o_ucnt);
    int*   gcurC = (int*)(ws + o_gcurC);
    int*   gcurR = (int*)(ws + o_gcurR);
    int*   nsel  = (int*)(ws + o_misc);
    float* zp    = (float*)(ws + o_misc + 8);
    float* S     = (float*)(ws + o_misc + 256);
    float* ctx   = (float*)(ws + o_misc + 512);
    float* dinv  = (float*)(ws + o_dinv);
    float* dinv2 = (float*)(ws + o_dinv2);
    int*   rptr  = (int*)(ws + o_rptr);
    int*   rend  = (int*)(ws + o_rend);

    hipMemsetAsync(ws + o_zero, 0, zero_bytes, stream);

    ucnt_kernel<<<(BATCH + 255) / 256, 256, 0, stream>>>(users, ucnt);

    // fused single-pass bucket sort (fixed LDS slots + overflow fallback)
    sort_kernel<<<SLICES, 512, 0, stream>>>(row, col, ucnt, gcurC, gcurR,
                                            midC, midR, nsel, selc, selw);
    // fused: col CSR + row deg + embed->y0 conversion
    bfinal_kernel<<<NBUK, 1024, 0, stream>>>(midC, gcurC, midR, gcurR,
                                             (const float4*)embed, rptr, rend, srcS,
                                             dinv, dinv2, (uint2*)xa);

    // layers 1,2 full: y->y (dinv2), y->y (dinv2); layer 3 selective: y->x (dinv)
    int prop_blocks = ((NNODES + 1) * 8 + 255) / 256;
    prop_kernel<<<prop_blocks, 256, 0, stream>>>((const uint4*)xa, (uint4*)xb, rptr, rend, srcS, dinv2);
    prop_kernel<<<prop_blocks, 256, 0, stream>>>((const uint4*)xb, (uint4*)xa, rptr, rend, srcS, dinv2);
    prop_list_kernel<<<1024, 256, 0, stream>>>((const uint4*)xa, (uint4*)xb,
                                               rptr, rend, srcS, dinv,
                                               users, items, selc, nsel);
    // final x rows (users/items/sel) live in xb

    // batch softmax aggregation over selected edges (mx = 0, fused)
    ctx_part_kernel<<<64, 256, 0, stream>>>(xb, users, ctx);
    softmax_kernel<<<LOGIT_BLOCKS, 256, 0, stream>>>(xb, ctx, selc, selw, nsel, S, zp);

    // final scores
    score_kernel<<<(BATCH * 64 + 255) / 256, 256, 0, stream>>>(xb, users, items, S, zp, out);
}

// Round 10
// 256.137 us; speedup vs baseline: 1.0922x; 1.0010x over previous
//
#include <hip/hip_runtime.h>
#include <float.h>
#include <math.h>

#define NUM_USERS 100000
#define NUM_ITEMS 50000
#define NNODES    150000
#define DIM       64
#define NEDGE     2000000
#define BATCH     1024
#define SEL_CAP   (1 << 18)
#define LOGIT_BLOCKS 512

#define SLICES   1024                   // edge slices (all blocks resident: 4/CU)
#define EPS      1956                   // ceil(NEDGE/SLICES) rounded to x4
#define NBUK     293                    // buckets of 512 nodes (293*512=150016)
#define BCAP     8192                   // per-bucket CSR arena (exp 6826, +16 sigma)
#define SCAP     16                     // fixed slots per (bucket, slice); exp 6.7
#define OVF_CAP  4096                   // global overflow list (exp ~200 edges/run)

__device__ __forceinline__ float wave_sum64(float v) {
    #pragma unroll
    for (int off = 32; off > 0; off >>= 1) v += __shfl_xor(v, off, 64);
    return v;
}

__device__ __forceinline__ float bf2f(unsigned short s) {
    return __uint_as_float(((unsigned int)s) << 16);
}
__device__ __forceinline__ unsigned short f2bf(float f) {   // RNE
    unsigned int u = __float_as_uint(f);
    return (unsigned short)((u + 0x7fffu + ((u >> 16) & 1u)) >> 16);
}

// ---- bucket sort, single pass, deterministic (bucket,slice) slotting -----
// No global reservation atomics: every (bucket,slice) owns a fixed 16-slot
// region of mid2; per-region count bytes tell bfinal what's valid. Rare
// overflow (Poisson tail, ~200 edges/run) appends to a global list via
// atomics, consumed exactly in bfinal. Within-bucket order is arbitrary
// (re-ranked per node in bfinal).

__global__ __launch_bounds__(512) void sort_kernel(
        const int* __restrict__ row, const int* __restrict__ col,
        const int* __restrict__ ucnt,
        unsigned char* __restrict__ cntC8, unsigned char* __restrict__ cntR8,
        unsigned int* __restrict__ midC2, unsigned short* __restrict__ midR2,
        uint2* __restrict__ ovfC, unsigned int* __restrict__ ovfR,
        int* __restrict__ novfC_g, int* __restrict__ novfR_g,
        int* __restrict__ n_sel, int* __restrict__ sel_col, float* __restrict__ sel_w) {
    __shared__ unsigned int hc[NBUK], hr[NBUK];
    __shared__ unsigned int   stC[NBUK * SCAP];
    __shared__ unsigned short stR[NBUK * SCAP];
    __shared__ int lcnt, lbase;
    __shared__ int2 buf[256];
    int blk = blockIdx.x, t = threadIdx.x;
    for (int i = t; i < NBUK; i += 512) { hc[i] = 0; hr[i] = 0; }
    if (t == 0) lcnt = 0;
    __syncthreads();
    int e0 = blk * EPS;
    int e1 = e0 + EPS; if (e1 > NEDGE) e1 = NEDGE;
    // single edge pass: rank via LDS atomic -> fixed slot; selection fused;
    // overflow goes straight to the global list (rare)
    for (int base = e0 + t * 4; base < e1; base += 2048) {
        if (base + 4 <= e1) {
            int4 r4 = *(const int4*)(row + base);
            int4 c4 = *(const int4*)(col + base);
            #pragma unroll
            for (int q = 0; q < 4; ++q) {
                int c = (q == 0) ? c4.x : (q == 1) ? c4.y : (q == 2) ? c4.z : c4.w;
                int r = (q == 0) ? r4.x : (q == 1) ? r4.y : (q == 2) ? r4.z : r4.w;
                int bc = c >> 9;
                unsigned int kc = atomicAdd(&hc[bc], 1u);
                unsigned int v = ((unsigned int)(c & 511) << 18) | (unsigned int)r;
                if (kc < SCAP) stC[bc * SCAP + kc] = v;
                else { int i = atomicAdd(novfC_g, 1); if (i < OVF_CAP) ovfC[i] = make_uint2((unsigned int)bc, v); }
                int br = r >> 9;
                unsigned int kr = atomicAdd(&hr[br], 1u);
                if (kr < SCAP) stR[br * SCAP + kr] = (unsigned short)(r & 511);
                else { int i = atomicAdd(novfR_g, 1); if (i < OVF_CAP) ovfR[i] = ((unsigned int)br << 9) | (unsigned int)(r & 511); }
                int u = ucnt[r];
                if (u > 0) { int i = atomicAdd(&lcnt, 1); if (i < 256) buf[i] = make_int2(c, u); }
            }
        } else {
            for (int e = base; e < e1; ++e) {
                int r = row[e], c = col[e];
                int bc = c >> 9;
                unsigned int kc = atomicAdd(&hc[bc], 1u);
                unsigned int v = ((unsigned int)(c & 511) << 18) | (unsigned int)r;
                if (kc < SCAP) stC[bc * SCAP + kc] = v;
                else { int i = atomicAdd(novfC_g, 1); if (i < OVF_CAP) ovfC[i] = make_uint2((unsigned int)bc, v); }
                int br = r >> 9;
                unsigned int kr = atomicAdd(&hr[br], 1u);
                if (kr < SCAP) stR[br * SCAP + kr] = (unsigned short)(r & 511);
                else { int i = atomicAdd(novfR_g, 1); if (i < OVF_CAP) ovfR[i] = ((unsigned int)br << 9) | (unsigned int)(r & 511); }
                int u = ucnt[r];
                if (u > 0) { int i = atomicAdd(&lcnt, 1); if (i < 256) buf[i] = make_int2(c, u); }
            }
        }
    }
    __syncthreads();
    // write-out to this slice's fixed regions: mid2[(b*SLICES + blk)*SCAP + k]
    for (int j = t; j < NBUK * SCAP; j += 512) {
        int b = j >> 4, k = j & (SCAP - 1);
        unsigned int cc = hc[b]; if (cc > SCAP) cc = SCAP;
        if ((unsigned int)k < cc)
            midC2[(size_t)b * (SLICES * SCAP) + blk * SCAP + k] = stC[j];
        unsigned int cr = hr[b]; if (cr > SCAP) cr = SCAP;
        if ((unsigned int)k < cr)
            midR2[(size_t)b * (SLICES * SCAP) + blk * SCAP + k] = stR[j];
    }
    if (t < NBUK) {
        unsigned int cc = hc[t]; if (cc > SCAP) cc = SCAP;
        unsigned int cr = hr[t]; if (cr > SCAP) cr = SCAP;
        cntC8[(size_t)blk * NBUK + t] = (unsigned char)cc;
        cntR8[(size_t)blk * NBUK + t] = (unsigned char)cr;
    }
    if (t == 0) {
        int c = lcnt; c = c < 256 ? c : 256;
        lbase = atomicAdd(n_sel, c);
    }
    __syncthreads();
    // selection flush
    int c = lcnt; c = c < 256 ? c : 256;
    int b = lbase;
    for (int i = t; i < c; i += 512) {
        int o = b + i;
        if (o < SEL_CAP) { sel_col[o] = buf[i].x; sel_w[o] = (float)buf[i].y; }
    }
}

// ---- stage 2 (fused): col CSR + row deg/dinv + embed->bf16 y0 ------------

__global__ __launch_bounds__(1024) void bfinal_kernel(
        const unsigned int* __restrict__ midC2, const unsigned char* __restrict__ cntC8,
        const unsigned short* __restrict__ midR2, const unsigned char* __restrict__ cntR8,
        const uint2* __restrict__ ovfC, const unsigned int* __restrict__ ovfR,
        const int* __restrict__ novfC_g, const int* __restrict__ novfR_g,
        const float4* __restrict__ embed,
        int* __restrict__ rptr, int* __restrict__ rend, int* __restrict__ src_sorted,
        float* __restrict__ dinv, float* __restrict__ dinv2,
        uint2* __restrict__ y0) {
    __shared__ int cnt[512], sm[512], cur[512];
    __shared__ unsigned char lcC[SLICES], lcR[SLICES];
    __shared__ float dinvL[512];
    int b = blockIdx.x, t = threadIdx.x;
    // stage per-slice counts for this bucket
    if (t < SLICES) {
        lcC[t] = cntC8[(size_t)t * NBUK + b];
        lcR[t] = cntR8[(size_t)t * NBUK + b];
    }
    if (t < 512) cnt[t] = 0;
    __syncthreads();
    // --- col counts ---
    size_t cbase = (size_t)b * (SLICES * SCAP);
    for (int j = t; j < SLICES * SCAP; j += 1024) {
        if ((unsigned int)(j & (SCAP - 1)) < (unsigned int)lcC[j >> 4])
            atomicAdd(&cnt[midC2[cbase + j] >> 18], 1);
    }
    int noC = *novfC_g; if (noC > OVF_CAP) noC = OVF_CAP;
    for (int i = t; i < noC; i += 1024)
        if ((int)ovfC[i].x == b) atomicAdd(&cnt[ovfC[i].y >> 18], 1);
    __syncthreads();
    if (t < 512) sm[t] = cnt[t];
    __syncthreads();
    for (int off = 1; off < 512; off <<= 1) {
        int v = 0;
        if (t < 512 && t >= off) v = sm[t - off];
        __syncthreads();
        if (t < 512) sm[t] += v;
        __syncthreads();
    }
    int s0 = b * BCAP;
    if (t < 512) {
        int excl = s0 + sm[t] - cnt[t];
        int n = b * 512 + t;
        if (n < NNODES) { rptr[n] = excl; rend[n] = s0 + sm[t]; }
        cur[t] = excl;
    }
    if (b == 0 && t < 16) y0[(size_t)NNODES * 16 + t] = make_uint2(0u, 0u); // sentinel zero row
    __syncthreads();
    // --- col scatter ---
    for (int j = t; j < SLICES * SCAP; j += 1024) {
        if ((unsigned int)(j & (SCAP - 1)) < (unsigned int)lcC[j >> 4]) {
            unsigned int v = midC2[cbase + j];
            int dst = atomicAdd(&cur[v >> 18], 1);
            src_sorted[dst] = (int)(v & 0x3FFFFu);
        }
    }
    for (int i = t; i < noC; i += 1024)
        if ((int)ovfC[i].x == b) {
            unsigned int v = ovfC[i].y;
            int dst = atomicAdd(&cur[v >> 18], 1);
            src_sorted[dst] = (int)(v & 0x3FFFFu);
        }
    __syncthreads();
    // --- row deg ---
    if (t < 512) cnt[t] = 0;
    __syncthreads();
    for (int j = t; j < SLICES * SCAP; j += 1024) {
        if ((unsigned int)(j & (SCAP - 1)) < (unsigned int)lcR[j >> 4])
            atomicAdd(&cnt[midR2[cbase + j]], 1);
    }
    int noR = *novfR_g; if (noR > OVF_CAP) noR = OVF_CAP;
    for (int i = t; i < noR; i += 1024) {
        unsigned int pv = ovfR[i];
        if ((int)(pv >> 9) == b) atomicAdd(&cnt[pv & 511u], 1);
    }
    __syncthreads();
    if (t < 512) {
        int n = b * 512 + t;
        if (n < NNODES) {
            float d = fmaxf((float)cnt[t], 1.0f);
            float di = rsqrtf(d);
            dinv[n] = di; dinv2[n] = 1.0f / d;
            dinvL[t] = di;
        }
    }
    __syncthreads();
    // --- cvt: y0 = bf16(dinv * embed) for this node range ---
    int nbase = b * 512;
    int nmax = NNODES - nbase; if (nmax > 512) nmax = 512;
    if (nmax < 0) nmax = 0;
    for (int i = t; i < nmax * 16; i += 1024) {
        int ln = i >> 4, slot = i & 15;
        float d = dinvL[ln];
        float4 v = embed[(size_t)(nbase + ln) * 16 + slot];
        unsigned int w0 = (unsigned int)f2bf(v.x * d) | ((unsigned int)f2bf(v.y * d) << 16);
        unsigned int w1 = (unsigned int)f2bf(v.z * d) | ((unsigned int)f2bf(v.w * d) << 16);
        y0[(size_t)(nbase + ln) * 16 + slot] = make_uint2(w0, w1);
    }
}

// ---- propagation: 8 lanes/node, uint4 (8 bf16)/lane; src-prefetch pipeline,
//      parallel sentinel tail (node NNODES is an always-zero row) -----------

#define ACC8(V) do { \
    a0 += __uint_as_float((V).x << 16); a1 += __uint_as_float((V).x & 0xffff0000u); \
    a2 += __uint_as_float((V).y << 16); a3 += __uint_as_float((V).y & 0xffff0000u); \
    a4 += __uint_as_float((V).z << 16); a5 += __uint_as_float((V).z & 0xffff0000u); \
    a6 += __uint_as_float((V).w << 16); a7 += __uint_as_float((V).w & 0xffff0000u); \
} while (0)

// shared gather body: accumulate neighbors of `node`, write x_out row
__device__ __forceinline__ void prop_node(
        const uint4* __restrict__ x_in, uint4* __restrict__ x_out,
        const int* __restrict__ ptr, const int* __restrict__ rend,
        const int* __restrict__ src,
        const float* __restrict__ scale, int node, int sl) {
    int i = ptr[node], e = rend[node];
    float sc = scale[node];
    float a0 = 0.f, a1 = 0.f, a2 = 0.f, a3 = 0.f;
    float a4 = 0.f, a5 = 0.f, a6 = 0.f, a7 = 0.f;
    int p0, p1, p2, p3;
    if (i + 4 <= e) { p0 = src[i]; p1 = src[i + 1]; p2 = src[i + 2]; p3 = src[i + 3]; }
    while (i + 8 <= e) {
        uint4 w0 = x_in[p0 * 8 + sl];
        uint4 w1 = x_in[p1 * 8 + sl];
        uint4 w2 = x_in[p2 * 8 + sl];
        uint4 w3 = x_in[p3 * 8 + sl];
        p0 = src[i + 4]; p1 = src[i + 5]; p2 = src[i + 6]; p3 = src[i + 7];
        i += 4;
        ACC8(w0); ACC8(w1); ACC8(w2); ACC8(w3);
    }
    if (i + 4 <= e) {
        uint4 w0 = x_in[p0 * 8 + sl];
        uint4 w1 = x_in[p1 * 8 + sl];
        uint4 w2 = x_in[p2 * 8 + sl];
        uint4 w3 = x_in[p3 * 8 + sl];
        i += 4;
        ACC8(w0); ACC8(w1); ACC8(w2); ACC8(w3);
    }
    if (i < e) {               // tail 1..3: clamp to sentinel zero row
        int q0 = src[i];
        int q1 = (i + 1 < e) ? src[i + 1] : NNODES;
        int q2 = (i + 2 < e) ? src[i + 2] : NNODES;
        uint4 w0 = x_in[q0 * 8 + sl];
        uint4 w1 = x_in[q1 * 8 + sl];
        uint4 w2 = x_in[q2 * 8 + sl];
        ACC8(w0); ACC8(w1); ACC8(w2);
    }
    uint4 o;
    o.x = (unsigned int)f2bf(a0 * sc) | ((unsigned int)f2bf(a1 * sc) << 16);
    o.y = (unsigned int)f2bf(a2 * sc) | ((unsigned int)f2bf(a3 * sc) << 16);
    o.z = (unsigned int)f2bf(a4 * sc) | ((unsigned int)f2bf(a5 * sc) << 16);
    o.w = (unsigned int)f2bf(a6 * sc) | ((unsigned int)f2bf(a7 * sc) << 16);
    x_out[(size_t)node * 8 + sl] = o;
}

__global__ __launch_bounds__(256, 8) void prop_kernel(
        const uint4* __restrict__ x_in, uint4* __restrict__ x_out,
        const int* __restrict__ ptr, const int* __restrict__ rend,
        const int* __restrict__ src,
        const float* __restrict__ scale) {
    int gid  = blockIdx.x * blockDim.x + threadIdx.x;
    int node = gid >> 3;       // 8 lanes per node
    int sl   = gid & 7;        // lane's 8-dim slot within the row
    if (node > NNODES) return;
    if (node == NNODES) {      // keep sentinel row zero for next layer
        x_out[(size_t)node * 8 + sl] = make_uint4(0u, 0u, 0u, 0u);
        return;
    }
    prop_node(x_in, x_out, ptr, rend, src, scale, node, sl);
}

// layer 3: only nodes consumed downstream — users, items+NUM_USERS, sel_col.
__global__ __launch_bounds__(256, 8) void prop_list_kernel(
        const uint4* __restrict__ x_in, uint4* __restrict__ x_out,
        const int* __restrict__ ptr, const int* __restrict__ rend,
        const int* __restrict__ src,
        const float* __restrict__ scale,
        const int* __restrict__ users, const int* __restrict__ items,
        const int* __restrict__ sel_col, const int* __restrict__ n_sel_p) {
    int n = *n_sel_p; if (n > SEL_CAP) n = SEL_CAP;
    int total = (2 * BATCH + n) * 8;
    int nth = gridDim.x * blockDim.x;
    for (int gid = blockIdx.x * blockDim.x + threadIdx.x; gid < total; gid += nth) {
        int li = gid >> 3;
        int sl = gid & 7;
        int node;
        if (li < BATCH) {
            node = users[li];
        } else if (li < 2 * BATCH) {
            node = items[li - BATCH] + NUM_USERS;
        } else {
            node = sel_col[li - 2 * BATCH];
        }
        prop_node(x_in, x_out, ptr, rend, src, scale, node, sl);
    }
}

// ---- batch / softmax part (x is bf16) -----------------------------------

__global__ void ucnt_kernel(const int* __restrict__ users, int* __restrict__ ucnt) {
    int b = blockIdx.x * blockDim.x + threadIdx.x;
    if (b < BATCH) atomicAdd(&ucnt[users[b]], 1);
}

// 64 blocks x 16 users; one atomicAdd per lane into zeroed ctx (raw sum).
__global__ __launch_bounds__(256) void ctx_part_kernel(
        const unsigned short* __restrict__ x, const int* __restrict__ users,
        float* __restrict__ ctx) {
    __shared__ float sm[256];
    int lane = threadIdx.x & 63, wl = threadIdx.x >> 6;
    int b0 = blockIdx.x * 16 + wl * 4;
    float acc = 0.0f;
    #pragma unroll
    for (int k = 0; k < 4; ++k)
        acc += bf2f(x[users[b0 + k] * DIM + lane]);
    sm[threadIdx.x] = acc;
    __syncthreads();
    if (wl == 0)
        atomicAdd(&ctx[lane], sm[lane] + sm[64 + lane] + sm[128 + lane] + sm[192 + lane]);
}

__global__ void softmax_kernel(const unsigned short* __restrict__ x,
                               const float* __restrict__ ctx,
                               const int* __restrict__ sel_col,
                               const float* __restrict__ sel_w,
                               const int* __restrict__ n_sel_p,
                               float* __restrict__ S, float* __restrict__ zp) {
    __shared__ float smS[4 * 64];
    __shared__ float smZ[4];
    int lane = threadIdx.x & 63, wl = threadIdx.x >> 6;
    int n = *n_sel_p; if (n > SEL_CAP) n = SEL_CAP;
    float c = ctx[lane] * (1.0f / BATCH);   // ctx holds raw sum over users
    float accS = 0.0f, accZ = 0.0f;
    int stride = gridDim.x * 4;
    for (int idx = blockIdx.x * 4 + wl; idx < n; idx += stride) {
        int node = sel_col[idx];
        float xv = bf2f(x[node * DIM + lane]);
        float v = wave_sum64(xv * c);
        float w = sel_w[idx] * __expf(v);
        accS = fmaf(w, xv, accS);
        accZ += w;
    }
    smS[wl * 64 + lane] = accS;
    if (lane == 0) smZ[wl] = accZ;
    __syncthreads();
    if (wl == 0) {
        float s = smS[lane] + smS[64 + lane] + smS[128 + lane] + smS[192 + lane];
        atomicAdd(&S[lane], s);
    }
    if (threadIdx.x == 0) atomicAdd(zp, smZ[0] + smZ[1] + smZ[2] + smZ[3]);
}

__global__ void score_kernel(const unsigned short* __restrict__ x, const int* __restrict__ users,
                             const int* __restrict__ items, const float* __restrict__ S,
                             const float* __restrict__ zp, float* __restrict__ out) {
    int gid = blockIdx.x * blockDim.x + threadIdx.x;
    int b = gid >> 6, lane = gid & 63;
    if (b >= BATCH) return;
    float z = fmaxf(*zp, 1e-12f);
    float na = S[lane] / z;
    int u = users[b], it = items[b] + NUM_USERS;
    float v = bf2f(x[u * DIM + lane]) * (bf2f(x[it * DIM + lane]) + na);
    v = wave_sum64(v);
    if (lane == 0) out[b] = 1.0f / (1.0f + __expf(-v));
}

// ---- launch -------------------------------------------------------------

extern "C" void kernel_launch(void* const* d_in, const int* in_sizes, int n_in,
                              void* d_out, int out_size, void* d_ws, size_t ws_size,
                              hipStream_t stream) {
    const float* embed = (const float*)d_in[0];
    const int*   edge  = (const int*)d_in[1];
    const int*   row   = edge;
    const int*   col   = edge + NEDGE;
    const int*   users = (const int*)d_in[2];
    const int*   items = (const int*)d_in[3];
    float*       out   = (float*)d_out;
    char*        ws    = (char*)d_ws;

    size_t off = 0;
    auto A = [&](size_t bytes) { size_t o = off; off += (bytes + 255) & ~(size_t)255; return o; };
    size_t o_midC2 = A((size_t)NBUK * SLICES * SCAP * 4);   // 19.2 MB
    size_t o_midR2 = A((size_t)NBUK * SLICES * SCAP * 2);   // 9.6 MB
    size_t o_xa    = A((size_t)(NNODES + 1) * DIM * 2);     // +1: sentinel zero row
    size_t o_xb    = A((size_t)(NNODES + 1) * DIM * 2);
    size_t o_src   = A((size_t)NBUK * BCAP * 4);            // 9.6 MB, alive thru prop
    size_t o_cntC8 = A((size_t)SLICES * NBUK);              // 300 KB
    size_t o_cntR8 = A((size_t)SLICES * NBUK);
    size_t o_ovfC  = A((size_t)OVF_CAP * 8);
    size_t o_ovfR  = A((size_t)OVF_CAP * 4);
    size_t o_selc  = A((size_t)SEL_CAP * 4);
    size_t o_selw  = A((size_t)SEL_CAP * 4);
    size_t o_zero  = off;                                   // ---- zeroed block ----
    size_t o_ucnt  = A((size_t)NNODES * 4);
    size_t o_misc  = A(1024);     // n_sel@0, z@8, S@256, ctx@512, novfC@768, novfR@772
    size_t zero_bytes = off - o_zero;                       // ---- end zero -------
    size_t o_dinv  = A((size_t)NNODES * 4);
    size_t o_dinv2 = A((size_t)NNODES * 4);
    size_t o_rptr  = A((size_t)NNODES * 4);
    size_t o_rend  = A((size_t)NNODES * 4);

    unsigned int*   midC2 = (unsigned int*)(ws + o_midC2);
    unsigned short* midR2 = (unsigned short*)(ws + o_midR2);
    unsigned short* xa   = (unsigned short*)(ws + o_xa);
    unsigned short* xb   = (unsigned short*)(ws + o_xb);
    int*   srcS  = (int*)(ws + o_src);
    unsigned char* cntC8 = (unsigned char*)(ws + o_cntC8);
    unsigned char* cntR8 = (unsigned char*)(ws + o_cntR8);
    uint2* ovfC  = (uint2*)(ws + o_ovfC);
    unsigned int* ovfR = (unsigned int*)(ws + o_ovfR);
    int*   selc  = (int*)(ws + o_selc);
    float* selw  = (float*)(ws + o_selw);
    int*   ucnt  = (int*)(ws + o_ucnt);
    int*   nsel  = (int*)(ws + o_misc);
    float* zp    = (float*)(ws + o_misc + 8);
    float* S     = (float*)(ws + o_misc + 256);
    float* ctx   = (float*)(ws + o_misc + 512);
    int*   novfC = (int*)(ws + o_misc + 768);
    int*   novfR = (int*)(ws + o_misc + 772);
    float* dinv  = (float*)(ws + o_dinv);
    float* dinv2 = (float*)(ws + o_dinv2);
    int*   rptr  = (int*)(ws + o_rptr);
    int*   rend  = (int*)(ws + o_rend);

    hipMemsetAsync(ws + o_zero, 0, zero_bytes, stream);

    ucnt_kernel<<<(BATCH + 255) / 256, 256, 0, stream>>>(users, ucnt);

    // single-pass bucket sort, deterministic slotting (no reservation atomics)
    sort_kernel<<<SLICES, 512, 0, stream>>>(row, col, ucnt, cntC8, cntR8,
                                            midC2, midR2, ovfC, ovfR, novfC, novfR,
                                            nsel, selc, selw);
    // fused: col CSR + row deg + embed->y0 conversion
    bfinal_kernel<<<NBUK, 1024, 0, stream>>>(midC2, cntC8, midR2, cntR8,
                                             ovfC, ovfR, novfC, novfR,
                                             (const float4*)embed, rptr, rend, srcS,
                                             dinv, dinv2, (uint2*)xa);

    // layers 1,2 full: y->y (dinv2), y->y (dinv2); layer 3 selective: y->x (dinv)
    int prop_blocks = ((NNODES + 1) * 8 + 255) / 256;
    prop_kernel<<<prop_blocks, 256, 0, stream>>>((const uint4*)xa, (uint4*)xb, rptr, rend, srcS, dinv2);
    prop_kernel<<<prop_blocks, 256, 0, stream>>>((const uint4*)xb, (uint4*)xa, rptr, rend, srcS, dinv2);
    prop_list_kernel<<<1024, 256, 0, stream>>>((const uint4*)xa, (uint4*)xb,
                                               rptr, rend, srcS, dinv,
                                               users, items, selc, nsel);
    // final x rows (users/items/sel) live in xb

    // batch softmax aggregation over selected edges (mx = 0, fused)
    ctx_part_kernel<<<64, 256, 0, stream>>>(xb, users, ctx);
    softmax_kernel<<<LOGIT_BLOCKS, 256, 0, stream>>>(xb, ctx, selc, selw, nsel, S, zp);

    // final scores
    score_kernel<<<(BATCH * 64 + 255) / 256, 256, 0, stream>>>(xb, users, items, S, zp, out);
}

// Round 11
// 248.446 us; speedup vs baseline: 1.1261x; 1.0310x over previous
//
#include <hip/hip_runtime.h>
#include <float.h>
#include <math.h>

#define NUM_USERS 100000
#define NUM_ITEMS 50000
#define NNODES    150000
#define DIM       64
#define NEDGE     2000000
#define BATCH     1024
#define SEL_CAP   (1 << 18)
#define LOGIT_BLOCKS 512

#define SLICES   1024                   // edge slices (all blocks resident: 4/CU)
#define EPS      1956                   // ceil(NEDGE/SLICES) rounded to x4
#define NBUK     293                    // buckets of 512 nodes (293*512=150016)
#define BCAP     8192                   // per-bucket CSR arena (exp 6826, +16 sigma)
#define SCAP     16                     // fixed slots per (bucket, slice); exp 6.7
#define OVF_CAP  4096                   // global overflow list (exp ~200 edges/run)

__device__ __forceinline__ float wave_sum64(float v) {
    #pragma unroll
    for (int off = 32; off > 0; off >>= 1) v += __shfl_xor(v, off, 64);
    return v;
}

__device__ __forceinline__ float bf2f(unsigned short s) {
    return __uint_as_float(((unsigned int)s) << 16);
}
__device__ __forceinline__ unsigned short f2bf(float f) {   // RNE
    unsigned int u = __float_as_uint(f);
    return (unsigned short)((u + 0x7fffu + ((u >> 16) & 1u)) >> 16);
}

// ---- bucket sort, single pass, deterministic (bucket,slice) slotting -----

__global__ __launch_bounds__(512) void sort_kernel(
        const int* __restrict__ row, const int* __restrict__ col,
        const int* __restrict__ ucnt,
        unsigned char* __restrict__ cntC8, unsigned char* __restrict__ cntR8,
        unsigned int* __restrict__ midC2, unsigned short* __restrict__ midR2,
        uint2* __restrict__ ovfC, unsigned int* __restrict__ ovfR,
        int* __restrict__ novfC_g, int* __restrict__ novfR_g,
        int* __restrict__ n_sel, int* __restrict__ sel_col, float* __restrict__ sel_w) {
    __shared__ unsigned int hc[NBUK], hr[NBUK];
    __shared__ unsigned int   stC[NBUK * SCAP];
    __shared__ unsigned short stR[NBUK * SCAP];
    __shared__ int lcnt, lbase;
    __shared__ int2 buf[256];
    int blk = blockIdx.x, t = threadIdx.x;
    for (int i = t; i < NBUK; i += 512) { hc[i] = 0; hr[i] = 0; }
    if (t == 0) lcnt = 0;
    __syncthreads();
    int e0 = blk * EPS;
    int e1 = e0 + EPS; if (e1 > NEDGE) e1 = NEDGE;
    for (int base = e0 + t * 4; base < e1; base += 2048) {
        if (base + 4 <= e1) {
            int4 r4 = *(const int4*)(row + base);
            int4 c4 = *(const int4*)(col + base);
            #pragma unroll
            for (int q = 0; q < 4; ++q) {
                int c = (q == 0) ? c4.x : (q == 1) ? c4.y : (q == 2) ? c4.z : c4.w;
                int r = (q == 0) ? r4.x : (q == 1) ? r4.y : (q == 2) ? r4.z : r4.w;
                int bc = c >> 9;
                unsigned int kc = atomicAdd(&hc[bc], 1u);
                unsigned int v = ((unsigned int)(c & 511) << 18) | (unsigned int)r;
                if (kc < SCAP) stC[bc * SCAP + kc] = v;
                else { int i = atomicAdd(novfC_g, 1); if (i < OVF_CAP) ovfC[i] = make_uint2((unsigned int)bc, v); }
                int br = r >> 9;
                unsigned int kr = atomicAdd(&hr[br], 1u);
                if (kr < SCAP) stR[br * SCAP + kr] = (unsigned short)(r & 511);
                else { int i = atomicAdd(novfR_g, 1); if (i < OVF_CAP) ovfR[i] = ((unsigned int)br << 9) | (unsigned int)(r & 511); }
                int u = ucnt[r];
                if (u > 0) { int i = atomicAdd(&lcnt, 1); if (i < 256) buf[i] = make_int2(c, u); }
            }
        } else {
            for (int e = base; e < e1; ++e) {
                int r = row[e], c = col[e];
                int bc = c >> 9;
                unsigned int kc = atomicAdd(&hc[bc], 1u);
                unsigned int v = ((unsigned int)(c & 511) << 18) | (unsigned int)r;
                if (kc < SCAP) stC[bc * SCAP + kc] = v;
                else { int i = atomicAdd(novfC_g, 1); if (i < OVF_CAP) ovfC[i] = make_uint2((unsigned int)bc, v); }
                int br = r >> 9;
                unsigned int kr = atomicAdd(&hr[br], 1u);
                if (kr < SCAP) stR[br * SCAP + kr] = (unsigned short)(r & 511);
                else { int i = atomicAdd(novfR_g, 1); if (i < OVF_CAP) ovfR[i] = ((unsigned int)br << 9) | (unsigned int)(r & 511); }
                int u = ucnt[r];
                if (u > 0) { int i = atomicAdd(&lcnt, 1); if (i < 256) buf[i] = make_int2(c, u); }
            }
        }
    }
    __syncthreads();
    for (int j = t; j < NBUK * SCAP; j += 512) {
        int b = j >> 4, k = j & (SCAP - 1);
        unsigned int cc = hc[b]; if (cc > SCAP) cc = SCAP;
        if ((unsigned int)k < cc)
            midC2[(size_t)b * (SLICES * SCAP) + blk * SCAP + k] = stC[j];
        unsigned int cr = hr[b]; if (cr > SCAP) cr = SCAP;
        if ((unsigned int)k < cr)
            midR2[(size_t)b * (SLICES * SCAP) + blk * SCAP + k] = stR[j];
    }
    if (t < NBUK) {
        unsigned int cc = hc[t]; if (cc > SCAP) cc = SCAP;
        unsigned int cr = hr[t]; if (cr > SCAP) cr = SCAP;
        cntC8[(size_t)blk * NBUK + t] = (unsigned char)cc;
        cntR8[(size_t)blk * NBUK + t] = (unsigned char)cr;
    }
    if (t == 0) {
        int c = lcnt; c = c < 256 ? c : 256;
        lbase = atomicAdd(n_sel, c);
    }
    __syncthreads();
    int c = lcnt; c = c < 256 ? c : 256;
    int b = lbase;
    for (int i = t; i < c; i += 512) {
        int o = b + i;
        if (o < SEL_CAP) { sel_col[o] = buf[i].x; sel_w[o] = (float)buf[i].y; }
    }
}

// ---- stage 2, split grid: blocks [0,NBUK) col CSR; [NBUK,2*NBUK) row+cvt --
// Col: count pass compacts valid entries into LDS stage[] (one global read),
// scan, scatter src_sorted from LDS. Row: deg count -> dinv/dinv2 -> y0 cvt.

__global__ __launch_bounds__(1024) void bfinal_kernel(
        const unsigned int* __restrict__ midC2, const unsigned char* __restrict__ cntC8,
        const unsigned short* __restrict__ midR2, const unsigned char* __restrict__ cntR8,
        const uint2* __restrict__ ovfC, const unsigned int* __restrict__ ovfR,
        const int* __restrict__ novfC_g, const int* __restrict__ novfR_g,
        const float4* __restrict__ embed,
        int* __restrict__ rptr, int* __restrict__ rend, int* __restrict__ src_sorted,
        float* __restrict__ dinv, float* __restrict__ dinv2,
        uint2* __restrict__ y0) {
    __shared__ int cnt[512], sm[512], cur[512];
    __shared__ unsigned int stage[BCAP];          // 32 KB compacted col entries
    __shared__ int nstage;
    __shared__ unsigned char lc[SLICES];
    __shared__ float dinvL[512];
    int bb = blockIdx.x, t = threadIdx.x;
    if (bb < NBUK) {
        // ---------------- col CSR for bucket b ----------------
        int b = bb;
        if (t < SLICES) lc[t] = cntC8[(size_t)t * NBUK + b];
        if (t < 512) cnt[t] = 0;
        if (t == 0) nstage = 0;
        __syncthreads();
        size_t cbase = (size_t)b * (SLICES * SCAP);
        for (int j = t; j < SLICES * SCAP; j += 1024) {
            if ((unsigned int)(j & (SCAP - 1)) < (unsigned int)lc[j >> 4]) {
                unsigned int v = midC2[cbase + j];
                atomicAdd(&cnt[v >> 18], 1);
                int i = atomicAdd(&nstage, 1);
                if (i < BCAP) stage[i] = v;
            }
        }
        int noC = *novfC_g; if (noC > OVF_CAP) noC = OVF_CAP;
        for (int i = t; i < noC; i += 1024) {
            if ((int)ovfC[i].x == b) {
                unsigned int v = ovfC[i].y;
                atomicAdd(&cnt[v >> 18], 1);
                int k = atomicAdd(&nstage, 1);
                if (k < BCAP) stage[k] = v;
            }
        }
        __syncthreads();
        if (t < 512) sm[t] = cnt[t];
        __syncthreads();
        for (int off = 1; off < 512; off <<= 1) {
            int v = 0;
            if (t < 512 && t >= off) v = sm[t - off];
            __syncthreads();
            if (t < 512) sm[t] += v;
            __syncthreads();
        }
        int s0 = b * BCAP;
        if (t < 512) {
            int excl = s0 + sm[t] - cnt[t];
            int n = b * 512 + t;
            if (n < NNODES) { rptr[n] = excl; rend[n] = s0 + sm[t]; }
            cur[t] = excl;
        }
        __syncthreads();
        int ns = nstage; if (ns > BCAP) ns = BCAP;
        for (int j = t; j < ns; j += 1024) {
            unsigned int v = stage[j];
            int dst = atomicAdd(&cur[v >> 18], 1);
            src_sorted[dst] = (int)(v & 0x3FFFFu);
        }
    } else {
        // ---------------- row deg + dinv + cvt for bucket b ----------------
        int b = bb - NBUK;
        if (t < SLICES) lc[t] = cntR8[(size_t)t * NBUK + b];
        if (t < 512) cnt[t] = 0;
        __syncthreads();
        size_t cbase = (size_t)b * (SLICES * SCAP);
        for (int j = t; j < SLICES * SCAP; j += 1024) {
            if ((unsigned int)(j & (SCAP - 1)) < (unsigned int)lc[j >> 4])
                atomicAdd(&cnt[midR2[cbase + j]], 1);
        }
        int noR = *novfR_g; if (noR > OVF_CAP) noR = OVF_CAP;
        for (int i = t; i < noR; i += 1024) {
            unsigned int pv = ovfR[i];
            if ((int)(pv >> 9) == b) atomicAdd(&cnt[pv & 511u], 1);
        }
        if (b == 0 && t < 16) y0[(size_t)NNODES * 16 + t] = make_uint2(0u, 0u); // sentinel
        __syncthreads();
        if (t < 512) {
            int n = b * 512 + t;
            if (n < NNODES) {
                float d = fmaxf((float)cnt[t], 1.0f);
                float di = rsqrtf(d);
                dinv[n] = di; dinv2[n] = 1.0f / d;
                dinvL[t] = di;
            }
        }
        __syncthreads();
        int nbase = b * 512;
        int nmax = NNODES - nbase; if (nmax > 512) nmax = 512;
        if (nmax < 0) nmax = 0;
        for (int i = t; i < nmax * 16; i += 1024) {
            int ln = i >> 4, slot = i & 15;
            float d = dinvL[ln];
            float4 v = embed[(size_t)(nbase + ln) * 16 + slot];
            unsigned int w0 = (unsigned int)f2bf(v.x * d) | ((unsigned int)f2bf(v.y * d) << 16);
            unsigned int w1 = (unsigned int)f2bf(v.z * d) | ((unsigned int)f2bf(v.w * d) << 16);
            y0[(size_t)(nbase + ln) * 16 + slot] = make_uint2(w0, w1);
        }
    }
}

// ---- propagation: 8 lanes/node, uint4 (8 bf16)/lane; src-prefetch pipeline,
//      parallel sentinel tail (node NNODES is an always-zero row) -----------

#define ACC8(V) do { \
    a0 += __uint_as_float((V).x << 16); a1 += __uint_as_float((V).x & 0xffff0000u); \
    a2 += __uint_as_float((V).y << 16); a3 += __uint_as_float((V).y & 0xffff0000u); \
    a4 += __uint_as_float((V).z << 16); a5 += __uint_as_float((V).z & 0xffff0000u); \
    a6 += __uint_as_float((V).w << 16); a7 += __uint_as_float((V).w & 0xffff0000u); \
} while (0)

__device__ __forceinline__ void prop_node(
        const uint4* __restrict__ x_in, uint4* __restrict__ x_out,
        const int* __restrict__ ptr, const int* __restrict__ rend,
        const int* __restrict__ src,
        const float* __restrict__ scale, int node, int sl) {
    int i = ptr[node], e = rend[node];
    float sc = scale[node];
    float a0 = 0.f, a1 = 0.f, a2 = 0.f, a3 = 0.f;
    float a4 = 0.f, a5 = 0.f, a6 = 0.f, a7 = 0.f;
    int p0, p1, p2, p3;
    if (i + 4 <= e) { p0 = src[i]; p1 = src[i + 1]; p2 = src[i + 2]; p3 = src[i + 3]; }
    while (i + 8 <= e) {
        uint4 w0 = x_in[p0 * 8 + sl];
        uint4 w1 = x_in[p1 * 8 + sl];
        uint4 w2 = x_in[p2 * 8 + sl];
        uint4 w3 = x_in[p3 * 8 + sl];
        p0 = src[i + 4]; p1 = src[i + 5]; p2 = src[i + 6]; p3 = src[i + 7];
        i += 4;
        ACC8(w0); ACC8(w1); ACC8(w2); ACC8(w3);
    }
    if (i + 4 <= e) {
        uint4 w0 = x_in[p0 * 8 + sl];
        uint4 w1 = x_in[p1 * 8 + sl];
        uint4 w2 = x_in[p2 * 8 + sl];
        uint4 w3 = x_in[p3 * 8 + sl];
        i += 4;
        ACC8(w0); ACC8(w1); ACC8(w2); ACC8(w3);
    }
    if (i < e) {               // tail 1..3: clamp to sentinel zero row
        int q0 = src[i];
        int q1 = (i + 1 < e) ? src[i + 1] : NNODES;
        int q2 = (i + 2 < e) ? src[i + 2] : NNODES;
        uint4 w0 = x_in[q0 * 8 + sl];
        uint4 w1 = x_in[q1 * 8 + sl];
        uint4 w2 = x_in[q2 * 8 + sl];
        ACC8(w0); ACC8(w1); ACC8(w2);
    }
    uint4 o;
    o.x = (unsigned int)f2bf(a0 * sc) | ((unsigned int)f2bf(a1 * sc) << 16);
    o.y = (unsigned int)f2bf(a2 * sc) | ((unsigned int)f2bf(a3 * sc) << 16);
    o.z = (unsigned int)f2bf(a4 * sc) | ((unsigned int)f2bf(a5 * sc) << 16);
    o.w = (unsigned int)f2bf(a6 * sc) | ((unsigned int)f2bf(a7 * sc) << 16);
    x_out[(size_t)node * 8 + sl] = o;
}

__global__ __launch_bounds__(256, 8) void prop_kernel(
        const uint4* __restrict__ x_in, uint4* __restrict__ x_out,
        const int* __restrict__ ptr, const int* __restrict__ rend,
        const int* __restrict__ src,
        const float* __restrict__ scale) {
    int gid  = blockIdx.x * blockDim.x + threadIdx.x;
    int node = gid >> 3;       // 8 lanes per node
    int sl   = gid & 7;        // lane's 8-dim slot within the row
    if (node > NNODES) return;
    if (node == NNODES) {      // keep sentinel row zero for next layer
        x_out[(size_t)node * 8 + sl] = make_uint4(0u, 0u, 0u, 0u);
        return;
    }
    prop_node(x_in, x_out, ptr, rend, src, scale, node, sl);
}

// layer 3: only nodes consumed downstream — users, items+NUM_USERS, sel_col.
__global__ __launch_bounds__(256, 8) void prop_list_kernel(
        const uint4* __restrict__ x_in, uint4* __restrict__ x_out,
        const int* __restrict__ ptr, const int* __restrict__ rend,
        const int* __restrict__ src,
        const float* __restrict__ scale,
        const int* __restrict__ users, const int* __restrict__ items,
        const int* __restrict__ sel_col, const int* __restrict__ n_sel_p) {
    int n = *n_sel_p; if (n > SEL_CAP) n = SEL_CAP;
    int total = (2 * BATCH + n) * 8;
    int nth = gridDim.x * blockDim.x;
    for (int gid = blockIdx.x * blockDim.x + threadIdx.x; gid < total; gid += nth) {
        int li = gid >> 3;
        int sl = gid & 7;
        int node;
        if (li < BATCH) {
            node = users[li];
        } else if (li < 2 * BATCH) {
            node = items[li - BATCH] + NUM_USERS;
        } else {
            node = sel_col[li - 2 * BATCH];
        }
        prop_node(x_in, x_out, ptr, rend, src, scale, node, sl);
    }
}

// ---- batch / softmax part (x is bf16) -----------------------------------

__global__ void ucnt_kernel(const int* __restrict__ users, int* __restrict__ ucnt) {
    int b = blockIdx.x * blockDim.x + threadIdx.x;
    if (b < BATCH) atomicAdd(&ucnt[users[b]], 1);
}

// 64 blocks x 16 users; one atomicAdd per lane into zeroed ctx (raw sum).
__global__ __launch_bounds__(256) void ctx_part_kernel(
        const unsigned short* __restrict__ x, const int* __restrict__ users,
        float* __restrict__ ctx) {
    __shared__ float sm[256];
    int lane = threadIdx.x & 63, wl = threadIdx.x >> 6;
    int b0 = blockIdx.x * 16 + wl * 4;
    float acc = 0.0f;
    #pragma unroll
    for (int k = 0; k < 4; ++k)
        acc += bf2f(x[users[b0 + k] * DIM + lane]);
    sm[threadIdx.x] = acc;
    __syncthreads();
    if (wl == 0)
        atomicAdd(&ctx[lane], sm[lane] + sm[64 + lane] + sm[128 + lane] + sm[192 + lane]);
}

__global__ void softmax_kernel(const unsigned short* __restrict__ x,
                               const float* __restrict__ ctx,
                               const int* __restrict__ sel_col,
                               const float* __restrict__ sel_w,
                               const int* __restrict__ n_sel_p,
                               float* __restrict__ S, float* __restrict__ zp) {
    __shared__ float smS[4 * 64];
    __shared__ float smZ[4];
    int lane = threadIdx.x & 63, wl = threadIdx.x >> 6;
    int n = *n_sel_p; if (n > SEL_CAP) n = SEL_CAP;
    float c = ctx[lane] * (1.0f / BATCH);   // ctx holds raw sum over users
    float accS = 0.0f, accZ = 0.0f;
    int stride = gridDim.x * 4;
    for (int idx = blockIdx.x * 4 + wl; idx < n; idx += stride) {
        int node = sel_col[idx];
        float xv = bf2f(x[node * DIM + lane]);
        float v = wave_sum64(xv * c);
        float w = sel_w[idx] * __expf(v);
        accS = fmaf(w, xv, accS);
        accZ += w;
    }
    smS[wl * 64 + lane] = accS;
    if (lane == 0) smZ[wl] = accZ;
    __syncthreads();
    if (wl == 0) {
        float s = smS[lane] + smS[64 + lane] + smS[128 + lane] + smS[192 + lane];
        atomicAdd(&S[lane], s);
    }
    if (threadIdx.x == 0) atomicAdd(zp, smZ[0] + smZ[1] + smZ[2] + smZ[3]);
}

__global__ void score_kernel(const unsigned short* __restrict__ x, const int* __restrict__ users,
                             const int* __restrict__ items, const float* __restrict__ S,
                             const float* __restrict__ zp, float* __restrict__ out) {
    int gid = blockIdx.x * blockDim.x + threadIdx.x;
    int b = gid >> 6, lane = gid & 63;
    if (b >= BATCH) return;
    float z = fmaxf(*zp, 1e-12f);
    float na = S[lane] / z;
    int u = users[b], it = items[b] + NUM_USERS;
    float v = bf2f(x[u * DIM + lane]) * (bf2f(x[it * DIM + lane]) + na);
    v = wave_sum64(v);
    if (lane == 0) out[b] = 1.0f / (1.0f + __expf(-v));
}

// ---- launch -------------------------------------------------------------

extern "C" void kernel_launch(void* const* d_in, const int* in_sizes, int n_in,
                              void* d_out, int out_size, void* d_ws, size_t ws_size,
                              hipStream_t stream) {
    const float* embed = (const float*)d_in[0];
    const int*   edge  = (const int*)d_in[1];
    const int*   row   = edge;
    const int*   col   = edge + NEDGE;
    const int*   users = (const int*)d_in[2];
    const int*   items = (const int*)d_in[3];
    float*       out   = (float*)d_out;
    char*        ws    = (char*)d_ws;

    size_t off = 0;
    auto A = [&](size_t bytes) { size_t o = off; off += (bytes + 255) & ~(size_t)255; return o; };
    size_t o_midC2 = A((size_t)NBUK * SLICES * SCAP * 4);   // 19.2 MB
    size_t o_midR2 = A((size_t)NBUK * SLICES * SCAP * 2);   // 9.6 MB
    size_t o_xa    = A((size_t)(NNODES + 1) * DIM * 2);     // +1: sentinel zero row
    size_t o_xb    = A((size_t)(NNODES + 1) * DIM * 2);
    size_t o_src   = A((size_t)NBUK * BCAP * 4);            // 9.6 MB, alive thru prop
    size_t o_cntC8 = A((size_t)SLICES * NBUK);              // 300 KB
    size_t o_cntR8 = A((size_t)SLICES * NBUK);
    size_t o_ovfC  = A((size_t)OVF_CAP * 8);
    size_t o_ovfR  = A((size_t)OVF_CAP * 4);
    size_t o_selc  = A((size_t)SEL_CAP * 4);
    size_t o_selw  = A((size_t)SEL_CAP * 4);
    size_t o_zero  = off;                                   // ---- zeroed block ----
    size_t o_ucnt  = A((size_t)NNODES * 4);
    size_t o_misc  = A(1024);     // n_sel@0, z@8, S@256, ctx@512, novfC@768, novfR@772
    size_t zero_bytes = off - o_zero;                       // ---- end zero -------
    size_t o_dinv  = A((size_t)NNODES * 4);
    size_t o_dinv2 = A((size_t)NNODES * 4);
    size_t o_rptr  = A((size_t)NNODES * 4);
    size_t o_rend  = A((size_t)NNODES * 4);

    unsigned int*   midC2 = (unsigned int*)(ws + o_midC2);
    unsigned short* midR2 = (unsigned short*)(ws + o_midR2);
    unsigned short* xa   = (unsigned short*)(ws + o_xa);
    unsigned short* xb   = (unsigned short*)(ws + o_xb);
    int*   srcS  = (int*)(ws + o_src);
    unsigned char* cntC8 = (unsigned char*)(ws + o_cntC8);
    unsigned char* cntR8 = (unsigned char*)(ws + o_cntR8);
    uint2* ovfC  = (uint2*)(ws + o_ovfC);
    unsigned int* ovfR = (unsigned int*)(ws + o_ovfR);
    int*   selc  = (int*)(ws + o_selc);
    float* selw  = (float*)(ws + o_selw);
    int*   ucnt  = (int*)(ws + o_ucnt);
    int*   nsel  = (int*)(ws + o_misc);
    float* zp    = (float*)(ws + o_misc + 8);
    float* S     = (float*)(ws + o_misc + 256);
    float* ctx   = (float*)(ws + o_misc + 512);
    int*   novfC = (int*)(ws + o_misc + 768);
    int*   novfR = (int*)(ws + o_misc + 772);
    float* dinv  = (float*)(ws + o_dinv);
    float* dinv2 = (float*)(ws + o_dinv2);
    int*   rptr  = (int*)(ws + o_rptr);
    int*   rend  = (int*)(ws + o_rend);

    hipMemsetAsync(ws + o_zero, 0, zero_bytes, stream);

    ucnt_kernel<<<(BATCH + 255) / 256, 256, 0, stream>>>(users, ucnt);

    // single-pass bucket sort, deterministic slotting (no reservation atomics)
    sort_kernel<<<SLICES, 512, 0, stream>>>(row, col, ucnt, cntC8, cntR8,
                                            midC2, midR2, ovfC, ovfR, novfC, novfR,
                                            nsel, selc, selw);
    // split grid: col CSR (NBUK blocks) + row deg/dinv/cvt (NBUK blocks)
    bfinal_kernel<<<2 * NBUK, 1024, 0, stream>>>(midC2, cntC8, midR2, cntR8,
                                                 ovfC, ovfR, novfC, novfR,
                                                 (const float4*)embed, rptr, rend, srcS,
                                                 dinv, dinv2, (uint2*)xa);

    // layers 1,2 full: y->y (dinv2), y->y (dinv2); layer 3 selective: y->x (dinv)
    int prop_blocks = ((NNODES + 1) * 8 + 255) / 256;
    prop_kernel<<<prop_blocks, 256, 0, stream>>>((const uint4*)xa, (uint4*)xb, rptr, rend, srcS, dinv2);
    prop_kernel<<<prop_blocks, 256, 0, stream>>>((const uint4*)xb, (uint4*)xa, rptr, rend, srcS, dinv2);
    prop_list_kernel<<<1024, 256, 0, stream>>>((const uint4*)xa, (uint4*)xb,
                                               rptr, rend, srcS, dinv,
                                               users, items, selc, nsel);
    // final x rows (users/items/sel) live in xb

    // batch softmax aggregation over selected edges (mx = 0, fused)
    ctx_part_kernel<<<64, 256, 0, stream>>>(xb, users, ctx);
    softmax_kernel<<<LOGIT_BLOCKS, 256, 0, stream>>>(xb, ctx, selc, selw, nsel, S, zp);

    // final scores
    score_kernel<<<(BATCH * 64 + 255) / 256, 256, 0, stream>>>(xb, users, items, S, zp, out);
}